// Round 1
// baseline (10563.030 us; speedup 1.0000x reference)
//
#include <hip/hip_runtime.h>

#define NN 50000
#define NE 800000
#define NG 128
#define DIM 128
#define OUTD 64
#define NCONV 4

// ---------------- edge scatter: agg[dst] += h[src] -----------------
__global__ __launch_bounds__(256) void k_scatter(const float* __restrict__ h,
                                                 const int* __restrict__ src,
                                                 const int* __restrict__ dst,
                                                 float* __restrict__ agg)
{
    int t = threadIdx.x;
    int e = blockIdx.x * 4 + (t >> 6);
    if (e >= NE) return;
    int l = t & 63;
    int s = src[e], d = dst[e];
    float2 v = *reinterpret_cast<const float2*>(h + (size_t)s * DIM + l * 2);
    float* p = agg + (size_t)d * DIM + l * 2;
    atomicAdd(p, v.x);
    atomicAdd(p + 1, v.y);
}

// ---------------- pooled[gid[n]] += h[n] ---------------------------
__global__ __launch_bounds__(256) void k_pool(const float* __restrict__ h,
                                              const int* __restrict__ gid,
                                              float* __restrict__ pooled)
{
    int idx = blockIdx.x * 256 + threadIdx.x; // node*32 + c4
    int n = idx >> 5, c4 = idx & 31;
    if (n >= NN) return;
    float4 v = ((const float4*)h)[(size_t)n * 32 + c4];
    int g = gid[n];
    float* p = pooled + (size_t)g * DIM + c4 * 4;
    atomicAdd(p + 0, v.x);
    atomicAdd(p + 1, v.y);
    atomicAdd(p + 2, v.z);
    atomicAdd(p + 3, v.w);
}

// ---------------- fused GEMM + BN stat accumulation ----------------
// MODE 0: xeff = X + Xadd          (layer input: agg + h)
// MODE 1: xeff = relu(X*a + c)     (BN1 affine + relu on z1)
// Z = xeff @ W  (M=NN, K=DIM, N=DIM); colsum/colsq += column stats of Z
__device__ inline void fma4(const float4 xv, const float4 w0, const float4 w1,
                            const float4 w2, const float4 w3, float* accRow)
{
    accRow[0] = fmaf(xv.x, w0.x, accRow[0]); accRow[0] = fmaf(xv.y, w1.x, accRow[0]);
    accRow[0] = fmaf(xv.z, w2.x, accRow[0]); accRow[0] = fmaf(xv.w, w3.x, accRow[0]);
    accRow[1] = fmaf(xv.x, w0.y, accRow[1]); accRow[1] = fmaf(xv.y, w1.y, accRow[1]);
    accRow[1] = fmaf(xv.z, w2.y, accRow[1]); accRow[1] = fmaf(xv.w, w3.y, accRow[1]);
    accRow[2] = fmaf(xv.x, w0.z, accRow[2]); accRow[2] = fmaf(xv.y, w1.z, accRow[2]);
    accRow[2] = fmaf(xv.z, w2.z, accRow[2]); accRow[2] = fmaf(xv.w, w3.z, accRow[2]);
    accRow[3] = fmaf(xv.x, w0.w, accRow[3]); accRow[3] = fmaf(xv.y, w1.w, accRow[3]);
    accRow[3] = fmaf(xv.z, w2.w, accRow[3]); accRow[3] = fmaf(xv.w, w3.w, accRow[3]);
}

template<int MODE>
__global__ __launch_bounds__(256, 2) void k_gemm_bn(
    const float* __restrict__ X, const float* __restrict__ Xadd,
    const float* __restrict__ a, const float* __restrict__ c,
    const float* __restrict__ W, float* __restrict__ Z,
    float* __restrict__ colsum, float* __restrict__ colsq)
{
    __shared__ float Wl[DIM * DIM];  // 64 KB
    __shared__ float Xl[32 * DIM];   // 16 KB (reused for stat reduction)
    const int t = threadIdx.x;
    const int row0 = blockIdx.x * 32;

    { // stage W (row-major [k][n]) into LDS
        float4* Wv = (float4*)Wl;
        const float4* Wg = (const float4*)W;
        #pragma unroll
        for (int i = 0; i < 16; ++i) Wv[t + i * 256] = Wg[t + i * 256];
    }
    { // stage 32 input rows, applying the input transform
        const float4* Xv = (const float4*)X;
        #pragma unroll
        for (int ii = 0; ii < 4; ++ii) {
            int idx = t + ii * 256;          // = r*32 + k4
            int r = idx >> 5, k4 = idx & 31;
            int grow = row0 + r;
            float4 v = make_float4(0.f, 0.f, 0.f, 0.f);
            if (grow < NN) {
                v = Xv[(size_t)grow * 32 + k4];
                if (MODE == 0) {
                    float4 u = ((const float4*)Xadd)[(size_t)grow * 32 + k4];
                    v.x += u.x; v.y += u.y; v.z += u.z; v.w += u.w;
                } else {
                    float4 av = ((const float4*)a)[k4];
                    float4 cv = ((const float4*)c)[k4];
                    v.x = fmaxf(fmaf(v.x, av.x, cv.x), 0.f);
                    v.y = fmaxf(fmaf(v.y, av.y, cv.y), 0.f);
                    v.z = fmaxf(fmaf(v.z, av.z, cv.z), 0.f);
                    v.w = fmaxf(fmaf(v.w, av.w, cv.w), 0.f);
                }
            }
            ((float4*)Xl)[idx] = v;
        }
    }
    __syncthreads();

    const int cg = t & 31, rg = t >> 5;      // colgroup (4 cols), rowgroup (4 rows)
    float acc[4][4] = {};
    #pragma unroll
    for (int k4 = 0; k4 < 32; ++k4) {
        const float4 w0 = ((float4*)Wl)[(k4 * 4 + 0) * 32 + cg];
        const float4 w1 = ((float4*)Wl)[(k4 * 4 + 1) * 32 + cg];
        const float4 w2 = ((float4*)Wl)[(k4 * 4 + 2) * 32 + cg];
        const float4 w3 = ((float4*)Wl)[(k4 * 4 + 3) * 32 + cg];
        #pragma unroll
        for (int i = 0; i < 4; ++i) {
            float4 xv = ((float4*)Xl)[(rg * 4 + i) * 32 + k4];
            fma4(xv, w0, w1, w2, w3, acc[i]);
        }
    }

    // store Z and per-thread column partials
    float ps[4] = {0.f, 0.f, 0.f, 0.f}, pq[4] = {0.f, 0.f, 0.f, 0.f};
    #pragma unroll
    for (int i = 0; i < 4; ++i) {
        int grow = row0 + rg * 4 + i;
        if (grow < NN) {
            float4 o = make_float4(acc[i][0], acc[i][1], acc[i][2], acc[i][3]);
            ((float4*)Z)[(size_t)grow * 32 + cg] = o;
            #pragma unroll
            for (int j = 0; j < 4; ++j) {
                ps[j] += acc[i][j];
                pq[j] += acc[i][j] * acc[i][j];
            }
        }
    }
    __syncthreads();  // everyone done reading Xl
    float* redS = Xl;             // [8][128]
    float* redQ = Xl + 8 * 128;   // [8][128]
    ((float4*)(redS + rg * 128))[cg] = make_float4(ps[0], ps[1], ps[2], ps[3]);
    ((float4*)(redQ + rg * 128))[cg] = make_float4(pq[0], pq[1], pq[2], pq[3]);
    __syncthreads();
    if (t < DIM) {
        float s = 0.f, q = 0.f;
        #pragma unroll
        for (int r8 = 0; r8 < 8; ++r8) { s += redS[r8 * 128 + t]; q += redQ[r8 * 128 + t]; }
        atomicAdd(colsum + t, s);
        atomicAdd(colsq + t, q);
    }
}

// ---------------- BN stats -> affine (a, c) ------------------------
__global__ __launch_bounds__(128) void k_bnstats(const float* __restrict__ colsum,
                                                 const float* __restrict__ colsq,
                                                 const float* __restrict__ g,
                                                 const float* __restrict__ b,
                                                 float* __restrict__ a,
                                                 float* __restrict__ c)
{
    int t = threadIdx.x;
    const float invM = 1.f / (float)NN;
    float m = colsum[t] * invM;
    float v = colsq[t] * invM - m * m;
    float s = g[t] * rsqrtf(v + 1e-5f);
    a[t] = s;
    c[t] = b[t] - m * s;
}

// ------------- BN2 affine + relu -> h_next, + pooling --------------
__global__ __launch_bounds__(256) void k_bnpool(const float* __restrict__ z,
                                                const float* __restrict__ a,
                                                const float* __restrict__ c,
                                                const int* __restrict__ gid,
                                                float* __restrict__ hout,
                                                float* __restrict__ pooled)
{
    int idx = blockIdx.x * 256 + threadIdx.x; // node*32 + c4
    int n = idx >> 5, c4 = idx & 31;
    if (n >= NN) return;
    float4 v = ((const float4*)z)[(size_t)n * 32 + c4];
    float4 av = ((const float4*)a)[c4];
    float4 cv = ((const float4*)c)[c4];
    v.x = fmaxf(fmaf(v.x, av.x, cv.x), 0.f);
    v.y = fmaxf(fmaf(v.y, av.y, cv.y), 0.f);
    v.z = fmaxf(fmaf(v.z, av.z, cv.z), 0.f);
    v.w = fmaxf(fmaf(v.w, av.w, cv.w), 0.f);
    ((float4*)hout)[(size_t)n * 32 + c4] = v;
    int g = gid[n];
    float* p = pooled + (size_t)g * DIM + c4 * 4;
    atomicAdd(p + 0, v.x);
    atomicAdd(p + 1, v.y);
    atomicAdd(p + 2, v.z);
    atomicAdd(p + 3, v.w);
}

// ---------------- final: score = sum_i pooled_i @ predW_i + predb_i ----
__global__ __launch_bounds__(64) void k_score(const float* __restrict__ pooled, // [5][128][128]
                                              const float* __restrict__ predW,  // [5][128][64]
                                              const float* __restrict__ predb,  // [5][64]
                                              float* __restrict__ out)          // [128][64]
{
    int g = blockIdx.x;
    int o = threadIdx.x;
    float s = 0.f;
    for (int i = 0; i < 5; ++i) {
        const float* pr = pooled + (size_t)i * NG * DIM + (size_t)g * DIM;
        const float* Wp = predW + (size_t)i * DIM * OUTD;
        float acc = 0.f;
        #pragma unroll 4
        for (int k = 0; k < DIM; ++k) acc = fmaf(pr[k], Wp[k * OUTD + o], acc);
        s += acc + predb[i * OUTD + o];
    }
    out[(size_t)g * OUTD + o] = s;
}

extern "C" void kernel_launch(void* const* d_in, const int* in_sizes, int n_in,
                              void* d_out, int out_size, void* d_ws, size_t ws_size,
                              hipStream_t stream)
{
    const float* h     = (const float*)d_in[0];
    const int*   esrc  = (const int*)d_in[1];
    const int*   edst  = (const int*)d_in[2];
    const int*   gid   = (const int*)d_in[3];
    const float* W1    = (const float*)d_in[4];
    const float* bn1g  = (const float*)d_in[5];
    const float* bn1b  = (const float*)d_in[6];
    const float* W2    = (const float*)d_in[7];
    const float* bn2g  = (const float*)d_in[8];
    const float* bn2b  = (const float*)d_in[9];
    const float* predW = (const float*)d_in[10];
    const float* predb = (const float*)d_in[11];
    float* out = (float*)d_out;

    float* ws = (float*)d_ws;
    const size_t NF = (size_t)NN * DIM;        // 6.4M floats
    float* agg    = ws;                        // also reused as z2
    float* z1     = ws + NF;
    float* hbuf   = ws + 2 * NF;
    float* pooled = ws + 3 * NF;               // 5*128*128 = 81920
    float* stats  = pooled + 5 * NG * DIM;     // 4 layers * 1024

    // zero pooled + stats (ws is poisoned 0xAA before every call)
    hipMemsetAsync(pooled, 0, (5 * NG * DIM + NCONV * 1024) * sizeof(float), stream);

    // pooled[0] from the input h
    k_pool<<<(NN * 32 + 255) / 256, 256, 0, stream>>>(h, gid, pooled);

    const float* hcur = h;
    for (int i = 0; i < NCONV; ++i) {
        float* st = stats + i * 1024;
        // [0]=sum1 [128]=sq1 [256]=a1 [384]=c1 [512]=sum2 [640]=sq2 [768]=a2 [896]=c2
        hipMemsetAsync(agg, 0, NF * sizeof(float), stream);
        k_scatter<<<(NE + 3) / 4, 256, 0, stream>>>(hcur, esrc, edst, agg);
        k_gemm_bn<0><<<(NN + 31) / 32, 256, 0, stream>>>(
            agg, hcur, nullptr, nullptr, W1 + (size_t)i * DIM * DIM, z1, st, st + 128);
        k_bnstats<<<1, 128, 0, stream>>>(st, st + 128, bn1g + i * DIM, bn1b + i * DIM,
                                         st + 256, st + 384);
        k_gemm_bn<1><<<(NN + 31) / 32, 256, 0, stream>>>(
            z1, nullptr, st + 256, st + 384, W2 + (size_t)i * DIM * DIM, agg /*=z2*/,
            st + 512, st + 640);
        k_bnstats<<<1, 128, 0, stream>>>(st + 512, st + 640, bn2g + i * DIM, bn2b + i * DIM,
                                         st + 768, st + 896);
        k_bnpool<<<(NN * 32 + 255) / 256, 256, 0, stream>>>(
            agg, st + 768, st + 896, gid, hbuf, pooled + (size_t)(i + 1) * NG * DIM);
        hcur = hbuf;
    }

    k_score<<<NG, OUTD, 0, stream>>>(pooled, predW, predb, out);
}

// Round 2
// 2041.654 us; speedup vs baseline: 5.1738x; 5.1738x over previous
//
#include <hip/hip_runtime.h>

#define NN 50000
#define NE 800000
#define NG 128
#define DIM 128
#define OUTD 64
#define NCONV 4

// ================= CSR build =================
__global__ __launch_bounds__(256) void k_degree(const int* __restrict__ dst,
                                                int* __restrict__ deg)
{
    int e = blockIdx.x * 256 + threadIdx.x;
    if (e < NE) atomicAdd(&deg[dst[e]], 1);
}

__global__ __launch_bounds__(1024) void k_scan(const int* __restrict__ deg,
                                               int* __restrict__ rowptr,
                                               int* __restrict__ cursor)
{
    __shared__ int partial[1024];
    const int t = threadIdx.x;
    const int CH = 49;                 // 1024*49 >= 50000
    const int base = t * CH;
    int s = 0;
    for (int i = 0; i < CH; ++i) {
        int idx = base + i;
        if (idx < NN) s += deg[idx];
    }
    partial[t] = s;
    __syncthreads();
    for (int off = 1; off < 1024; off <<= 1) {
        int v = (t >= off) ? partial[t - off] : 0;
        __syncthreads();
        partial[t] += v;
        __syncthreads();
    }
    int run = (t == 0) ? 0 : partial[t - 1];
    if (t == 0) rowptr[NN] = partial[1023];
    for (int i = 0; i < CH; ++i) {
        int idx = base + i;
        if (idx < NN) {
            rowptr[idx] = run;
            cursor[idx] = run;
            run += deg[idx];
        }
    }
}

__global__ __launch_bounds__(256) void k_fill(const int* __restrict__ src,
                                              const int* __restrict__ dst,
                                              int* __restrict__ cursor,
                                              int* __restrict__ csr)
{
    int e = blockIdx.x * 256 + threadIdx.x;
    if (e >= NE) return;
    int pos = atomicAdd(&cursor[dst[e]], 1);
    csr[pos] = src[e];
}

// ============ gather: agg[n] = h[n] + sum_{s in N(n)} h[s] ============
__global__ __launch_bounds__(256) void k_gather(const float* __restrict__ h,
                                                const int* __restrict__ rowptr,
                                                const int* __restrict__ csr,
                                                float* __restrict__ agg)
{
    int t = threadIdx.x;
    int n = blockIdx.x * 4 + (t >> 6);
    if (n >= NN) return;
    int l = t & 63;
    const float2* hp = (const float2*)h;
    float2 v = hp[(size_t)n * 64 + l];          // self term
    int beg = rowptr[n], end = rowptr[n + 1];
    for (int p = beg; p < end; ++p) {
        int s = csr[p];
        float2 u = hp[(size_t)s * 64 + l];
        v.x += u.x; v.y += u.y;
    }
    ((float2*)agg)[(size_t)n * 64 + l] = v;
}

// ================= pooled[gid[n]] += h[n] =================
__global__ __launch_bounds__(256) void k_pool(const float* __restrict__ h,
                                              const int* __restrict__ gid,
                                              float* __restrict__ pooled)
{
    int idx = blockIdx.x * 256 + threadIdx.x; // node*32 + c4
    int n = idx >> 5, c4 = idx & 31;
    if (n >= NN) return;
    float4 v = ((const float4*)h)[(size_t)n * 32 + c4];
    int g = gid[n];
    float* p = pooled + (size_t)g * DIM + c4 * 4;
    atomicAdd(p + 0, v.x);
    atomicAdd(p + 1, v.y);
    atomicAdd(p + 2, v.z);
    atomicAdd(p + 3, v.w);
}

// ============ fused GEMM + BN stat accumulation ============
// AFFINE=false: xeff = X
// AFFINE=true : xeff = relu(X*a + c)
// Z = xeff @ W ; colsum/colsq accumulate column stats of Z.
// W read directly from global (L1/L2-resident 64 KB, broadcast addresses).
__device__ inline void fma4(const float4 xv, const float4 w0, const float4 w1,
                            const float4 w2, const float4 w3, float* accRow)
{
    accRow[0] = fmaf(xv.x, w0.x, accRow[0]); accRow[0] = fmaf(xv.y, w1.x, accRow[0]);
    accRow[0] = fmaf(xv.z, w2.x, accRow[0]); accRow[0] = fmaf(xv.w, w3.x, accRow[0]);
    accRow[1] = fmaf(xv.x, w0.y, accRow[1]); accRow[1] = fmaf(xv.y, w1.y, accRow[1]);
    accRow[1] = fmaf(xv.z, w2.y, accRow[1]); accRow[1] = fmaf(xv.w, w3.y, accRow[1]);
    accRow[2] = fmaf(xv.x, w0.z, accRow[2]); accRow[2] = fmaf(xv.y, w1.z, accRow[2]);
    accRow[2] = fmaf(xv.z, w2.z, accRow[2]); accRow[2] = fmaf(xv.w, w3.z, accRow[2]);
    accRow[3] = fmaf(xv.x, w0.w, accRow[3]); accRow[3] = fmaf(xv.y, w1.w, accRow[3]);
    accRow[3] = fmaf(xv.z, w2.w, accRow[3]); accRow[3] = fmaf(xv.w, w3.w, accRow[3]);
}

template<bool AFFINE>
__global__ __launch_bounds__(256) void k_gemm_bn(
    const float* __restrict__ X,
    const float* __restrict__ a, const float* __restrict__ c,
    const float* __restrict__ W, float* __restrict__ Z,
    float* __restrict__ colsum, float* __restrict__ colsq)
{
    __shared__ float Xl[32 * DIM];   // 16 KB; reused for stat reduction
    const int t = threadIdx.x;
    const int row0 = blockIdx.x * 32;

    { // stage 32 input rows, applying the input transform
        const float4* Xv = (const float4*)X;
        #pragma unroll
        for (int ii = 0; ii < 4; ++ii) {
            int idx = t + ii * 256;          // = r*32 + k4
            int r = idx >> 5, k4 = idx & 31;
            int grow = row0 + r;
            float4 v = make_float4(0.f, 0.f, 0.f, 0.f);
            if (grow < NN) {
                v = Xv[(size_t)grow * 32 + k4];
                if (AFFINE) {
                    float4 av = ((const float4*)a)[k4];
                    float4 cv = ((const float4*)c)[k4];
                    v.x = fmaxf(fmaf(v.x, av.x, cv.x), 0.f);
                    v.y = fmaxf(fmaf(v.y, av.y, cv.y), 0.f);
                    v.z = fmaxf(fmaf(v.z, av.z, cv.z), 0.f);
                    v.w = fmaxf(fmaf(v.w, av.w, cv.w), 0.f);
                }
            }
            ((float4*)Xl)[idx] = v;
        }
    }
    __syncthreads();

    const int cg = t & 31, rg = t >> 5;      // colgroup (4 cols), rowgroup (4 rows)
    const float4* Wg = (const float4*)W;
    float acc[4][4] = {};
    #pragma unroll 4
    for (int k4 = 0; k4 < 32; ++k4) {
        const float4 w0 = Wg[(k4 * 4 + 0) * 32 + cg];
        const float4 w1 = Wg[(k4 * 4 + 1) * 32 + cg];
        const float4 w2 = Wg[(k4 * 4 + 2) * 32 + cg];
        const float4 w3 = Wg[(k4 * 4 + 3) * 32 + cg];
        #pragma unroll
        for (int i = 0; i < 4; ++i) {
            float4 xv = ((float4*)Xl)[(rg * 4 + i) * 32 + k4];
            fma4(xv, w0, w1, w2, w3, acc[i]);
        }
    }

    // store Z and per-thread column partials
    float ps[4] = {0.f, 0.f, 0.f, 0.f}, pq[4] = {0.f, 0.f, 0.f, 0.f};
    #pragma unroll
    for (int i = 0; i < 4; ++i) {
        int grow = row0 + rg * 4 + i;
        if (grow < NN) {
            float4 o = make_float4(acc[i][0], acc[i][1], acc[i][2], acc[i][3]);
            ((float4*)Z)[(size_t)grow * 32 + cg] = o;
            #pragma unroll
            for (int j = 0; j < 4; ++j) {
                ps[j] += acc[i][j];
                pq[j] += acc[i][j] * acc[i][j];
            }
        }
    }
    __syncthreads();  // everyone done reading Xl
    float* redS = Xl;             // [8][128]
    float* redQ = Xl + 8 * 128;   // [8][128]
    ((float4*)(redS + rg * 128))[cg] = make_float4(ps[0], ps[1], ps[2], ps[3]);
    ((float4*)(redQ + rg * 128))[cg] = make_float4(pq[0], pq[1], pq[2], pq[3]);
    __syncthreads();
    if (t < DIM) {
        float s = 0.f, q = 0.f;
        #pragma unroll
        for (int r8 = 0; r8 < 8; ++r8) { s += redS[r8 * 128 + t]; q += redQ[r8 * 128 + t]; }
        atomicAdd(colsum + t, s);
        atomicAdd(colsq + t, q);
    }
}

// ================= BN stats -> affine (a, c) =================
__global__ __launch_bounds__(128) void k_bnstats(const float* __restrict__ colsum,
                                                 const float* __restrict__ colsq,
                                                 const float* __restrict__ g,
                                                 const float* __restrict__ b,
                                                 float* __restrict__ a,
                                                 float* __restrict__ c)
{
    int t = threadIdx.x;
    const float invM = 1.f / (float)NN;
    float m = colsum[t] * invM;
    float v = colsq[t] * invM - m * m;
    float s = g[t] * rsqrtf(v + 1e-5f);
    a[t] = s;
    c[t] = b[t] - m * s;
}

// ============ BN2 affine + relu -> h_next, + pooling ============
__global__ __launch_bounds__(256) void k_bnpool(const float* __restrict__ z,
                                                const float* __restrict__ a,
                                                const float* __restrict__ c,
                                                const int* __restrict__ gid,
                                                float* __restrict__ hout,
                                                float* __restrict__ pooled)
{
    int idx = blockIdx.x * 256 + threadIdx.x; // node*32 + c4
    int n = idx >> 5, c4 = idx & 31;
    if (n >= NN) return;
    float4 v = ((const float4*)z)[(size_t)n * 32 + c4];
    float4 av = ((const float4*)a)[c4];
    float4 cv = ((const float4*)c)[c4];
    v.x = fmaxf(fmaf(v.x, av.x, cv.x), 0.f);
    v.y = fmaxf(fmaf(v.y, av.y, cv.y), 0.f);
    v.z = fmaxf(fmaf(v.z, av.z, cv.z), 0.f);
    v.w = fmaxf(fmaf(v.w, av.w, cv.w), 0.f);
    ((float4*)hout)[(size_t)n * 32 + c4] = v;
    int g = gid[n];
    float* p = pooled + (size_t)g * DIM + c4 * 4;
    atomicAdd(p + 0, v.x);
    atomicAdd(p + 1, v.y);
    atomicAdd(p + 2, v.z);
    atomicAdd(p + 3, v.w);
}

// ======= final: score = sum_i pooled_i @ predW_i + predb_i =======
__global__ __launch_bounds__(64) void k_score(const float* __restrict__ pooled, // [5][128][128]
                                              const float* __restrict__ predW,  // [5][128][64]
                                              const float* __restrict__ predb,  // [5][64]
                                              float* __restrict__ out)          // [128][64]
{
    int g = blockIdx.x;
    int o = threadIdx.x;
    float s = 0.f;
    for (int i = 0; i < 5; ++i) {
        const float* pr = pooled + (size_t)i * NG * DIM + (size_t)g * DIM;
        const float* Wp = predW + (size_t)i * DIM * OUTD;
        float acc = 0.f;
        #pragma unroll 4
        for (int k = 0; k < DIM; ++k) acc = fmaf(pr[k], Wp[k * OUTD + o], acc);
        s += acc + predb[i * OUTD + o];
    }
    out[(size_t)g * OUTD + o] = s;
}

extern "C" void kernel_launch(void* const* d_in, const int* in_sizes, int n_in,
                              void* d_out, int out_size, void* d_ws, size_t ws_size,
                              hipStream_t stream)
{
    const float* h     = (const float*)d_in[0];
    const int*   esrc  = (const int*)d_in[1];
    const int*   edst  = (const int*)d_in[2];
    const int*   gid   = (const int*)d_in[3];
    const float* W1    = (const float*)d_in[4];
    const float* bn1g  = (const float*)d_in[5];
    const float* bn1b  = (const float*)d_in[6];
    const float* W2    = (const float*)d_in[7];
    const float* bn2g  = (const float*)d_in[8];
    const float* bn2b  = (const float*)d_in[9];
    const float* predW = (const float*)d_in[10];
    const float* predb = (const float*)d_in[11];
    float* out = (float*)d_out;

    float* ws = (float*)d_ws;
    const size_t NF = (size_t)NN * DIM;        // 6.4M floats
    float* agg    = ws;                        // also reused as z2
    float* z1     = ws + NF;
    float* hbuf   = ws + 2 * NF;
    float* pooled = ws + 3 * NF;               // 5*128*128
    float* stats  = pooled + 5 * NG * DIM;     // 4 layers * 1024

    int* ideg   = (int*)(stats + NCONV * 1024);
    int* rowptr = ideg + NN;                   // NN+1
    int* cursor = rowptr + NN + 1;
    int* csr    = cursor + NN;                 // NE

    // zero accumulators (ws is poisoned 0xAA before every call)
    hipMemsetAsync(pooled, 0, (5 * NG * DIM + NCONV * 1024) * sizeof(float), stream);
    hipMemsetAsync(ideg, 0, NN * sizeof(int), stream);

    // build CSR (dst -> list of src), once per call
    k_degree<<<(NE + 255) / 256, 256, 0, stream>>>(edst, ideg);
    k_scan<<<1, 1024, 0, stream>>>(ideg, rowptr, cursor);
    k_fill<<<(NE + 255) / 256, 256, 0, stream>>>(esrc, edst, cursor, csr);

    // pooled[0] from the input h
    k_pool<<<(NN * 32 + 255) / 256, 256, 0, stream>>>(h, gid, pooled);

    const float* hcur = h;
    for (int i = 0; i < NCONV; ++i) {
        float* st = stats + i * 1024;
        // [0]=sum1 [128]=sq1 [256]=a1 [384]=c1 [512]=sum2 [640]=sq2 [768]=a2 [896]=c2
        k_gather<<<(NN + 3) / 4, 256, 0, stream>>>(hcur, rowptr, csr, agg);
        k_gemm_bn<false><<<(NN + 31) / 32, 256, 0, stream>>>(
            agg, nullptr, nullptr, W1 + (size_t)i * DIM * DIM, z1, st, st + 128);
        k_bnstats<<<1, 128, 0, stream>>>(st, st + 128, bn1g + i * DIM, bn1b + i * DIM,
                                         st + 256, st + 384);
        k_gemm_bn<true><<<(NN + 31) / 32, 256, 0, stream>>>(
            z1, st + 256, st + 384, W2 + (size_t)i * DIM * DIM, agg /*=z2*/,
            st + 512, st + 640);
        k_bnstats<<<1, 128, 0, stream>>>(st + 512, st + 640, bn2g + i * DIM, bn2b + i * DIM,
                                         st + 768, st + 896);
        k_bnpool<<<(NN * 32 + 255) / 256, 256, 0, stream>>>(
            agg, st + 768, st + 896, gid, hbuf, pooled + (size_t)(i + 1) * NG * DIM);
        hcur = hbuf;
    }

    k_score<<<NG, OUTD, 0, stream>>>(pooled, predW, predb, out);
}

// Round 4
// 1295.058 us; speedup vs baseline: 8.1564x; 1.5765x over previous
//
#include <hip/hip_runtime.h>

#define NN 50000
#define NE 800000
#define NG 128
#define DIM 128
#define OUTD 64
#define NCONV 4

// ================= CSR build =================
__global__ __launch_bounds__(256) void k_degree(const int* __restrict__ dst,
                                                int* __restrict__ deg)
{
    int e = blockIdx.x * 256 + threadIdx.x;
    if (e < NE) atomicAdd(&deg[dst[e]], 1);
}

__global__ __launch_bounds__(1024) void k_scan(const int* __restrict__ deg,
                                               int* __restrict__ rowptr,
                                               int* __restrict__ cursor)
{
    __shared__ int partial[1024];
    const int t = threadIdx.x;
    const int CH = 49;                 // 1024*49 >= 50000
    const int base = t * CH;
    int s = 0;
    for (int i = 0; i < CH; ++i) {
        int idx = base + i;
        if (idx < NN) s += deg[idx];
    }
    partial[t] = s;
    __syncthreads();
    for (int off = 1; off < 1024; off <<= 1) {
        int v = (t >= off) ? partial[t - off] : 0;
        __syncthreads();
        partial[t] += v;
        __syncthreads();
    }
    int run = (t == 0) ? 0 : partial[t - 1];
    if (t == 0) rowptr[NN] = partial[1023];
    for (int i = 0; i < CH; ++i) {
        int idx = base + i;
        if (idx < NN) {
            rowptr[idx] = run;
            cursor[idx] = run;
            run += deg[idx];
        }
    }
}

__global__ __launch_bounds__(256) void k_fill(const int* __restrict__ src,
                                              const int* __restrict__ dst,
                                              int* __restrict__ cursor,
                                              int* __restrict__ csr)
{
    int e = blockIdx.x * 256 + threadIdx.x;
    if (e >= NE) return;
    int pos = atomicAdd(&cursor[dst[e]], 1);
    csr[pos] = src[e];
}

// ====== graph segment boundaries from sorted gid: gstart[g] ======
__global__ __launch_bounds__(256) void k_bounds(const int* __restrict__ gid,
                                                int* __restrict__ gstart)
{
    int n = blockIdx.x * 256 + threadIdx.x;
    if (n >= NN) return;
    int g = gid[n];
    int gp = (n == 0) ? -1 : gid[n - 1];
    for (int x = gp + 1; x <= g; ++x) gstart[x] = n;
    if (n == NN - 1)
        for (int x = g + 1; x <= NG; ++x) gstart[x] = NN;
}

// ==== gather: agg[n] = f(h[n]) + sum_{s in N(n)} f(h[s]); f = relu(affine) or id ====
template<bool AFFINE>
__global__ __launch_bounds__(256) void k_gather(const float* __restrict__ h,
                                                const float* __restrict__ a,
                                                const float* __restrict__ c,
                                                const int* __restrict__ rowptr,
                                                const int* __restrict__ csr,
                                                float* __restrict__ agg)
{
    int t = threadIdx.x;
    int n = blockIdx.x * 4 + (t >> 6);
    if (n >= NN) return;
    int l = t & 63;
    const float2* hp = (const float2*)h;
    float2 av, cv;
    if (AFFINE) { av = ((const float2*)a)[l]; cv = ((const float2*)c)[l]; }
    float2 v = hp[(size_t)n * 64 + l];          // self term
    if (AFFINE) {
        v.x = fmaxf(fmaf(v.x, av.x, cv.x), 0.f);
        v.y = fmaxf(fmaf(v.y, av.y, cv.y), 0.f);
    }
    int beg = rowptr[n], end = rowptr[n + 1];
    for (int p = beg; p < end; ++p) {
        int s = csr[p];
        float2 u = hp[(size_t)s * 64 + l];
        if (AFFINE) {
            u.x = fmaxf(fmaf(u.x, av.x, cv.x), 0.f);
            u.y = fmaxf(fmaf(u.y, av.y, cv.y), 0.f);
        }
        v.x += u.x; v.y += u.y;
    }
    ((float2*)agg)[(size_t)n * 64 + l] = v;
}

// ===== segmented pooling: pooled[g] += sum_{n in graph g} f(z[n]) =====
template<bool AFFINE>
__global__ __launch_bounds__(256) void k_poolseg(const float* __restrict__ z,
                                                 const float* __restrict__ a,
                                                 const float* __restrict__ c,
                                                 const int* __restrict__ gstart,
                                                 float* __restrict__ pooled)
{
    const int g = blockIdx.x >> 2, split = blockIdx.x & 3;
    const int s = gstart[g], e = gstart[g + 1];
    const int len = e - s;
    const int chunk = (len + 3) >> 2;
    const int rs = s + split * chunk;
    const int re = min(e, rs + chunk);
    const int c4 = threadIdx.x & 31, rl = threadIdx.x >> 5;
    float4 av, cv;
    if (AFFINE) { av = ((const float4*)a)[c4]; cv = ((const float4*)c)[c4]; }
    float4 acc = make_float4(0.f, 0.f, 0.f, 0.f);
    for (int r = rs + rl; r < re; r += 8) {
        float4 v = ((const float4*)z)[(size_t)r * 32 + c4];
        if (AFFINE) {
            v.x = fmaxf(fmaf(v.x, av.x, cv.x), 0.f);
            v.y = fmaxf(fmaf(v.y, av.y, cv.y), 0.f);
            v.z = fmaxf(fmaf(v.z, av.z, cv.z), 0.f);
            v.w = fmaxf(fmaf(v.w, av.w, cv.w), 0.f);
        }
        acc.x += v.x; acc.y += v.y; acc.z += v.z; acc.w += v.w;
    }
    __shared__ float4 red[8][32];
    red[rl][c4] = acc;
    __syncthreads();
    if (rl == 0) {
        float4 s4 = red[0][c4];
        #pragma unroll
        for (int r8 = 1; r8 < 8; ++r8) {
            float4 u = red[r8][c4];
            s4.x += u.x; s4.y += u.y; s4.z += u.z; s4.w += u.w;
        }
        float* p = pooled + (size_t)g * DIM + c4 * 4;
        atomicAdd(p + 0, s4.x);
        atomicAdd(p + 1, s4.y);
        atomicAdd(p + 2, s4.z);
        atomicAdd(p + 3, s4.w);
    }
}

// ============ fused GEMM + BN stat accumulation ============
__device__ inline void fma4(const float4 xv, const float4 w0, const float4 w1,
                            const float4 w2, const float4 w3, float* accRow)
{
    accRow[0] = fmaf(xv.x, w0.x, accRow[0]); accRow[0] = fmaf(xv.y, w1.x, accRow[0]);
    accRow[0] = fmaf(xv.z, w2.x, accRow[0]); accRow[0] = fmaf(xv.w, w3.x, accRow[0]);
    accRow[1] = fmaf(xv.x, w0.y, accRow[1]); accRow[1] = fmaf(xv.y, w1.y, accRow[1]);
    accRow[1] = fmaf(xv.z, w2.y, accRow[1]); accRow[1] = fmaf(xv.w, w3.y, accRow[1]);
    accRow[2] = fmaf(xv.x, w0.z, accRow[2]); accRow[2] = fmaf(xv.y, w1.z, accRow[2]);
    accRow[2] = fmaf(xv.z, w2.z, accRow[2]); accRow[2] = fmaf(xv.w, w3.z, accRow[2]);
    accRow[3] = fmaf(xv.x, w0.w, accRow[3]); accRow[3] = fmaf(xv.y, w1.w, accRow[3]);
    accRow[3] = fmaf(xv.z, w2.w, accRow[3]); accRow[3] = fmaf(xv.w, w3.w, accRow[3]);
}

template<bool AFFINE>
__global__ __launch_bounds__(256) void k_gemm_bn(
    const float* __restrict__ X,
    const float* __restrict__ a, const float* __restrict__ c,
    const float* __restrict__ W, float* __restrict__ Z,
    float* __restrict__ colsum, float* __restrict__ colsq)
{
    __shared__ float Xl[32 * DIM];   // 16 KB; reused for stat reduction
    const int t = threadIdx.x;
    const int row0 = blockIdx.x * 32;

    { // stage 32 input rows, applying the input transform
        const float4* Xv = (const float4*)X;
        #pragma unroll
        for (int ii = 0; ii < 4; ++ii) {
            int idx = t + ii * 256;          // = r*32 + k4
            int r = idx >> 5, k4 = idx & 31;
            int grow = row0 + r;
            float4 v = make_float4(0.f, 0.f, 0.f, 0.f);
            if (grow < NN) {
                v = Xv[(size_t)grow * 32 + k4];
                if (AFFINE) {
                    float4 av = ((const float4*)a)[k4];
                    float4 cv = ((const float4*)c)[k4];
                    v.x = fmaxf(fmaf(v.x, av.x, cv.x), 0.f);
                    v.y = fmaxf(fmaf(v.y, av.y, cv.y), 0.f);
                    v.z = fmaxf(fmaf(v.z, av.z, cv.z), 0.f);
                    v.w = fmaxf(fmaf(v.w, av.w, cv.w), 0.f);
                }
            }
            ((float4*)Xl)[idx] = v;
        }
    }
    __syncthreads();

    const int cg = t & 31, rg = t >> 5;      // colgroup (4 cols), rowgroup (4 rows)
    const float4* Wg = (const float4*)W;
    float acc[4][4] = {};
    #pragma unroll 4
    for (int k4 = 0; k4 < 32; ++k4) {
        const float4 w0 = Wg[(k4 * 4 + 0) * 32 + cg];
        const float4 w1 = Wg[(k4 * 4 + 1) * 32 + cg];
        const float4 w2 = Wg[(k4 * 4 + 2) * 32 + cg];
        const float4 w3 = Wg[(k4 * 4 + 3) * 32 + cg];
        #pragma unroll
        for (int i = 0; i < 4; ++i) {
            float4 xv = ((float4*)Xl)[(rg * 4 + i) * 32 + k4];
            fma4(xv, w0, w1, w2, w3, acc[i]);
        }
    }

    // store Z and per-thread column partials
    float ps[4] = {0.f, 0.f, 0.f, 0.f}, pq[4] = {0.f, 0.f, 0.f, 0.f};
    #pragma unroll
    for (int i = 0; i < 4; ++i) {
        int grow = row0 + rg * 4 + i;
        if (grow < NN) {
            float4 o = make_float4(acc[i][0], acc[i][1], acc[i][2], acc[i][3]);
            ((float4*)Z)[(size_t)grow * 32 + cg] = o;
            #pragma unroll
            for (int j = 0; j < 4; ++j) {
                ps[j] += acc[i][j];
                pq[j] += acc[i][j] * acc[i][j];
            }
        }
    }
    __syncthreads();  // everyone done reading Xl
    float* redS = Xl;             // [8][128]
    float* redQ = Xl + 8 * 128;   // [8][128]
    ((float4*)(redS + rg * 128))[cg] = make_float4(ps[0], ps[1], ps[2], ps[3]);
    ((float4*)(redQ + rg * 128))[cg] = make_float4(pq[0], pq[1], pq[2], pq[3]);
    __syncthreads();
    if (t < DIM) {
        float s = 0.f, q = 0.f;
        #pragma unroll
        for (int r8 = 0; r8 < 8; ++r8) { s += redS[r8 * 128 + t]; q += redQ[r8 * 128 + t]; }
        atomicAdd(colsum + t, s);
        atomicAdd(colsq + t, q);
    }
}

// ================= BN stats -> affine (a, c) =================
__global__ __launch_bounds__(128) void k_bnstats(const float* __restrict__ colsum,
                                                 const float* __restrict__ colsq,
                                                 const float* __restrict__ g,
                                                 const float* __restrict__ b,
                                                 float* __restrict__ a,
                                                 float* __restrict__ c)
{
    int t = threadIdx.x;
    const float invM = 1.f / (float)NN;
    float m = colsum[t] * invM;
    float v = colsq[t] * invM - m * m;
    float s = g[t] * rsqrtf(v + 1e-5f);
    a[t] = s;
    c[t] = b[t] - m * s;
}

// ======= final: score = sum_i pooled_i @ predW_i + predb_i =======
__global__ __launch_bounds__(64) void k_score(const float* __restrict__ pooled, // [5][128][128]
                                              const float* __restrict__ predW,  // [5][128][64]
                                              const float* __restrict__ predb,  // [5][64]
                                              float* __restrict__ out)          // [128][64]
{
    int g = blockIdx.x;
    int o = threadIdx.x;
    float s = 0.f;
    for (int i = 0; i < 5; ++i) {
        const float* pr = pooled + (size_t)i * NG * DIM + (size_t)g * DIM;
        const float* Wp = predW + (size_t)i * DIM * OUTD;
        float acc = 0.f;
        #pragma unroll 4
        for (int k = 0; k < DIM; ++k) acc = fmaf(pr[k], Wp[k * OUTD + o], acc);
        s += acc + predb[i * OUTD + o];
    }
    out[(size_t)g * OUTD + o] = s;
}

extern "C" void kernel_launch(void* const* d_in, const int* in_sizes, int n_in,
                              void* d_out, int out_size, void* d_ws, size_t ws_size,
                              hipStream_t stream)
{
    const float* h     = (const float*)d_in[0];
    const int*   esrc  = (const int*)d_in[1];
    const int*   edst  = (const int*)d_in[2];
    const int*   gid   = (const int*)d_in[3];
    const float* W1    = (const float*)d_in[4];
    const float* bn1g  = (const float*)d_in[5];
    const float* bn1b  = (const float*)d_in[6];
    const float* W2    = (const float*)d_in[7];
    const float* bn2g  = (const float*)d_in[8];
    const float* bn2b  = (const float*)d_in[9];
    const float* predW = (const float*)d_in[10];
    const float* predb = (const float*)d_in[11];
    float* out = (float*)d_out;

    float* ws = (float*)d_ws;
    const size_t NF = (size_t)NN * DIM;        // 6.4M floats
    float* agg    = ws;
    float* z1     = ws + NF;
    float* Zb     = ws + 2 * NF;               // z2, reused every layer
    float* pooled = ws + 3 * NF;               // 5*128*128
    float* stats  = pooled + 5 * NG * DIM;     // 4 layers * 1024

    int* ideg   = (int*)(stats + NCONV * 1024);
    int* rowptr = ideg + NN;                   // NN+1
    int* cursor = rowptr + NN + 1;
    int* csr    = cursor + NN;                 // NE
    int* gstart = csr + NE;                    // NG+1

    // zero accumulators (ws is poisoned 0xAA before every call)
    hipMemsetAsync(pooled, 0, (5 * NG * DIM + NCONV * 1024) * sizeof(float), stream);
    hipMemsetAsync(ideg, 0, NN * sizeof(int), stream);

    // build CSR (dst -> list of src) + graph boundaries, once per call
    k_degree<<<(NE + 255) / 256, 256, 0, stream>>>(edst, ideg);
    k_scan<<<1, 1024, 0, stream>>>(ideg, rowptr, cursor);
    k_fill<<<(NE + 255) / 256, 256, 0, stream>>>(esrc, edst, cursor, csr);
    k_bounds<<<(NN + 255) / 256, 256, 0, stream>>>(gid, gstart);

    // pooled[0] from the input h (no affine)
    k_poolseg<false><<<NG * 4, 256, 0, stream>>>(h, nullptr, nullptr, gstart, pooled);

    for (int i = 0; i < NCONV; ++i) {
        float* st = stats + i * 1024;
        // [0]=sum1 [128]=sq1 [256]=a1 [384]=c1 [512]=sum2 [640]=sq2 [768]=a2 [896]=c2
        if (i == 0)
            k_gather<false><<<(NN + 3) / 4, 256, 0, stream>>>(h, nullptr, nullptr,
                                                              rowptr, csr, agg);
        else {
            float* stp = stats + (i - 1) * 1024;
            k_gather<true><<<(NN + 3) / 4, 256, 0, stream>>>(Zb, stp + 768, stp + 896,
                                                             rowptr, csr, agg);
        }
        k_gemm_bn<false><<<(NN + 31) / 32, 256, 0, stream>>>(
            agg, nullptr, nullptr, W1 + (size_t)i * DIM * DIM, z1, st, st + 128);
        k_bnstats<<<1, 128, 0, stream>>>(st, st + 128, bn1g + i * DIM, bn1b + i * DIM,
                                         st + 256, st + 384);
        k_gemm_bn<true><<<(NN + 31) / 32, 256, 0, stream>>>(
            z1, st + 256, st + 384, W2 + (size_t)i * DIM * DIM, Zb,
            st + 512, st + 640);
        k_bnstats<<<1, 128, 0, stream>>>(st + 512, st + 640, bn2g + i * DIM, bn2b + i * DIM,
                                         st + 768, st + 896);
        k_poolseg<true><<<NG * 4, 256, 0, stream>>>(Zb, st + 768, st + 896, gstart,
                                                    pooled + (size_t)(i + 1) * NG * DIM);
    }

    k_score<<<NG, OUTD, 0, stream>>>(pooled, predW, predb, out);
}

// Round 5
// 879.650 us; speedup vs baseline: 12.0082x; 1.4722x over previous
//
#include <hip/hip_runtime.h>

#define NN 50000
#define NE 800000
#define NG 128
#define DIM 128
#define OUTD 64
#define NCONV 4
#define NB 196          // ceil(NN/256)
#define BN_EPS 1e-5f

// ================= CSR build =================
__global__ __launch_bounds__(256) void k_degree(const int* __restrict__ dst,
                                                int* __restrict__ deg)
{
    int e = blockIdx.x * 256 + threadIdx.x;
    if (e < NE) atomicAdd(&deg[dst[e]], 1);
}

// --- hierarchical exclusive scan of deg[NN] -> rowptr/cursor ---
__global__ __launch_bounds__(256) void k_scan1(const int* __restrict__ deg,
                                               int* __restrict__ bsum)
{
    __shared__ int part[256];
    int t = threadIdx.x, idx = blockIdx.x * 256 + t;
    int v = (idx < NN) ? deg[idx] : 0;
    part[t] = v;
    __syncthreads();
    #pragma unroll
    for (int off = 1; off < 256; off <<= 1) {
        int u = (t >= off) ? part[t - off] : 0;
        __syncthreads();
        part[t] += u;
        __syncthreads();
    }
    if (t == 255) bsum[blockIdx.x] = part[255];
}

__global__ __launch_bounds__(256) void k_scan2(const int* __restrict__ bsum,
                                               int* __restrict__ boff)
{
    __shared__ int part[256];
    int t = threadIdx.x;
    int v = (t < NB) ? bsum[t] : 0;
    part[t] = v;
    __syncthreads();
    #pragma unroll
    for (int off = 1; off < 256; off <<= 1) {
        int u = (t >= off) ? part[t - off] : 0;
        __syncthreads();
        part[t] += u;
        __syncthreads();
    }
    if (t < NB) boff[t] = part[t] - v;   // exclusive
}

__global__ __launch_bounds__(256) void k_scan3(const int* __restrict__ deg,
                                               const int* __restrict__ boff,
                                               int* __restrict__ rowptr,
                                               int* __restrict__ cursor)
{
    __shared__ int part[256];
    int t = threadIdx.x, idx = blockIdx.x * 256 + t;
    int v = (idx < NN) ? deg[idx] : 0;
    part[t] = v;
    __syncthreads();
    #pragma unroll
    for (int off = 1; off < 256; off <<= 1) {
        int u = (t >= off) ? part[t - off] : 0;
        __syncthreads();
        part[t] += u;
        __syncthreads();
    }
    if (idx < NN) {
        int excl = part[t] - v + boff[blockIdx.x];
        rowptr[idx] = excl;
        cursor[idx] = excl;
    }
    if (idx == 0) rowptr[NN] = NE;
}

__global__ __launch_bounds__(256) void k_fill(const int* __restrict__ src,
                                              const int* __restrict__ dst,
                                              int* __restrict__ cursor,
                                              int* __restrict__ csr)
{
    int e = blockIdx.x * 256 + threadIdx.x;
    if (e >= NE) return;
    int pos = atomicAdd(&cursor[dst[e]], 1);
    csr[pos] = src[e];
}

// ====== graph segment boundaries from sorted gid ======
__global__ __launch_bounds__(256) void k_bounds(const int* __restrict__ gid,
                                                int* __restrict__ gstart)
{
    int n = blockIdx.x * 256 + threadIdx.x;
    if (n >= NN) return;
    int g = gid[n];
    int gp = (n == 0) ? -1 : gid[n - 1];
    for (int x = gp + 1; x <= g; ++x) gstart[x] = n;
    if (n == NN - 1)
        for (int x = g + 1; x <= NG; ++x) gstart[x] = NN;
}

// --- per-thread BN affine for 4 channels ch0..ch0+3 ---
__device__ inline void bn_affine4(const float* __restrict__ sumP,
                                  const float* __restrict__ sqP,
                                  const float* __restrict__ gP,
                                  const float* __restrict__ bP,
                                  int ch0, float4& av, float4& cv)
{
    const float invM = 1.f / (float)NN;
    #pragma unroll
    for (int j = 0; j < 4; ++j) {
        int ch = ch0 + j;
        float m = sumP[ch] * invM;
        float var = sqP[ch] * invM - m * m;
        float s = gP[ch] * rsqrtf(var + BN_EPS);
        (&av.x)[j] = s;
        (&cv.x)[j] = bP[ch] - m * s;
    }
}

__device__ inline float4 aff_relu(float4 v, const float4 av, const float4 cv)
{
    v.x = fmaxf(fmaf(v.x, av.x, cv.x), 0.f);
    v.y = fmaxf(fmaf(v.y, av.y, cv.y), 0.f);
    v.z = fmaxf(fmaf(v.z, av.z, cv.z), 0.f);
    v.w = fmaxf(fmaf(v.w, av.w, cv.w), 0.f);
    return v;
}

// ==== gather: agg[n] = f(h[n]) + sum_{s in N(n)} f(h[s]) ====
// 32 lanes per node (float4), 8 nodes per block, neighbor loop unrolled x4.
template<bool AFFINE>
__global__ __launch_bounds__(256) void k_gather(
    const float* __restrict__ h,
    const float* __restrict__ sumP, const float* __restrict__ sqP,
    const float* __restrict__ gP, const float* __restrict__ bP,
    const int* __restrict__ rowptr, const int* __restrict__ csr,
    float* __restrict__ agg)
{
    int t = threadIdx.x;
    int n = blockIdx.x * 8 + (t >> 5);
    if (n >= NN) return;
    int l = t & 31;
    float4 av, cv;
    if (AFFINE) bn_affine4(sumP, sqP, gP, bP, l * 4, av, cv);
    const float4* hp = (const float4*)h;
    float4 v = hp[(size_t)n * 32 + l];
    if (AFFINE) v = aff_relu(v, av, cv);
    int p = rowptr[n], end = rowptr[n + 1];
    for (; p + 4 <= end; p += 4) {
        int s0 = csr[p], s1 = csr[p + 1], s2 = csr[p + 2], s3 = csr[p + 3];
        float4 u0 = hp[(size_t)s0 * 32 + l];
        float4 u1 = hp[(size_t)s1 * 32 + l];
        float4 u2 = hp[(size_t)s2 * 32 + l];
        float4 u3 = hp[(size_t)s3 * 32 + l];
        if (AFFINE) {
            u0 = aff_relu(u0, av, cv); u1 = aff_relu(u1, av, cv);
            u2 = aff_relu(u2, av, cv); u3 = aff_relu(u3, av, cv);
        }
        v.x += u0.x + u1.x + u2.x + u3.x;
        v.y += u0.y + u1.y + u2.y + u3.y;
        v.z += u0.z + u1.z + u2.z + u3.z;
        v.w += u0.w + u1.w + u2.w + u3.w;
    }
    for (; p < end; ++p) {
        int s = csr[p];
        float4 u = hp[(size_t)s * 32 + l];
        if (AFFINE) u = aff_relu(u, av, cv);
        v.x += u.x; v.y += u.y; v.z += u.z; v.w += u.w;
    }
    ((float4*)agg)[(size_t)n * 32 + l] = v;
}

// ===== segmented pooling: pooled[g] += sum_{n in graph g} f(z[n]) =====
template<bool AFFINE>
__global__ __launch_bounds__(256) void k_poolseg(
    const float* __restrict__ z,
    const float* __restrict__ sumP, const float* __restrict__ sqP,
    const float* __restrict__ gP, const float* __restrict__ bP,
    const int* __restrict__ gstart, float* __restrict__ pooled)
{
    const int g = blockIdx.x >> 2, split = blockIdx.x & 3;
    const int s = gstart[g], e = gstart[g + 1];
    const int len = e - s;
    const int chunk = (len + 3) >> 2;
    const int rs = s + split * chunk;
    const int re = min(e, rs + chunk);
    const int c4 = threadIdx.x & 31, rl = threadIdx.x >> 5;
    float4 av, cv;
    if (AFFINE) bn_affine4(sumP, sqP, gP, bP, c4 * 4, av, cv);
    float4 acc = make_float4(0.f, 0.f, 0.f, 0.f);
    for (int r = rs + rl; r < re; r += 8) {
        float4 v = ((const float4*)z)[(size_t)r * 32 + c4];
        if (AFFINE) v = aff_relu(v, av, cv);
        acc.x += v.x; acc.y += v.y; acc.z += v.z; acc.w += v.w;
    }
    __shared__ float4 red[8][32];
    red[rl][c4] = acc;
    __syncthreads();
    if (rl == 0) {
        float4 s4 = red[0][c4];
        #pragma unroll
        for (int r8 = 1; r8 < 8; ++r8) {
            float4 u = red[r8][c4];
            s4.x += u.x; s4.y += u.y; s4.z += u.z; s4.w += u.w;
        }
        float* p = pooled + (size_t)g * DIM + c4 * 4;
        atomicAdd(p + 0, s4.x);
        atomicAdd(p + 1, s4.y);
        atomicAdd(p + 2, s4.z);
        atomicAdd(p + 3, s4.w);
    }
}

// ============ fused GEMM + BN stat accumulation ============
__device__ inline void fma4(const float4 xv, const float4 w0, const float4 w1,
                            const float4 w2, const float4 w3, float* accRow)
{
    accRow[0] = fmaf(xv.x, w0.x, accRow[0]); accRow[0] = fmaf(xv.y, w1.x, accRow[0]);
    accRow[0] = fmaf(xv.z, w2.x, accRow[0]); accRow[0] = fmaf(xv.w, w3.x, accRow[0]);
    accRow[1] = fmaf(xv.x, w0.y, accRow[1]); accRow[1] = fmaf(xv.y, w1.y, accRow[1]);
    accRow[1] = fmaf(xv.z, w2.y, accRow[1]); accRow[1] = fmaf(xv.w, w3.y, accRow[1]);
    accRow[2] = fmaf(xv.x, w0.z, accRow[2]); accRow[2] = fmaf(xv.y, w1.z, accRow[2]);
    accRow[2] = fmaf(xv.z, w2.z, accRow[2]); accRow[2] = fmaf(xv.w, w3.z, accRow[2]);
    accRow[3] = fmaf(xv.x, w0.w, accRow[3]); accRow[3] = fmaf(xv.y, w1.w, accRow[3]);
    accRow[3] = fmaf(xv.z, w2.w, accRow[3]); accRow[3] = fmaf(xv.w, w3.w, accRow[3]);
}

// 64-row tile, 256 threads, each thread 8 rows x 4 cols.
template<bool AFFINE>
__global__ __launch_bounds__(256) void k_gemm_bn(
    const float* __restrict__ X,
    const float* __restrict__ sumP, const float* __restrict__ sqP,
    const float* __restrict__ gP, const float* __restrict__ bP,
    const float* __restrict__ W, float* __restrict__ Z,
    float* __restrict__ colsum, float* __restrict__ colsq)
{
    __shared__ float Xl[64 * DIM];   // 32 KB
    const int t = threadIdx.x;
    const int row0 = blockIdx.x * 64;

    float4 av, cv;
    if (AFFINE) bn_affine4(sumP, sqP, gP, bP, (t & 31) * 4, av, cv);

    { // stage 64 input rows (k4 == t&31 for every ii)
        const float4* Xv = (const float4*)X;
        #pragma unroll
        for (int ii = 0; ii < 8; ++ii) {
            int idx = t + ii * 256;          // = r*32 + k4
            int r = idx >> 5, k4 = idx & 31;
            int grow = row0 + r;
            float4 v = make_float4(0.f, 0.f, 0.f, 0.f);
            if (grow < NN) {
                v = Xv[(size_t)grow * 32 + k4];
                if (AFFINE) v = aff_relu(v, av, cv);
            }
            ((float4*)Xl)[idx] = v;
        }
    }
    __syncthreads();

    const int cg = t & 31, rg = t >> 5;      // 4 cols, 8 rowgroups of 8 rows
    const float4* Wg = (const float4*)W;
    float acc[8][4] = {};
    #pragma unroll 2
    for (int k4 = 0; k4 < 32; ++k4) {
        const float4 w0 = Wg[(k4 * 4 + 0) * 32 + cg];
        const float4 w1 = Wg[(k4 * 4 + 1) * 32 + cg];
        const float4 w2 = Wg[(k4 * 4 + 2) * 32 + cg];
        const float4 w3 = Wg[(k4 * 4 + 3) * 32 + cg];
        #pragma unroll
        for (int i = 0; i < 8; ++i) {
            float4 xv = ((float4*)Xl)[(rg * 8 + i) * 32 + k4];
            fma4(xv, w0, w1, w2, w3, acc[i]);
        }
    }

    // store Z and per-thread column partials
    float ps[4] = {0.f, 0.f, 0.f, 0.f}, pq[4] = {0.f, 0.f, 0.f, 0.f};
    #pragma unroll
    for (int i = 0; i < 8; ++i) {
        int grow = row0 + rg * 8 + i;
        if (grow < NN) {
            float4 o = make_float4(acc[i][0], acc[i][1], acc[i][2], acc[i][3]);
            ((float4*)Z)[(size_t)grow * 32 + cg] = o;
            #pragma unroll
            for (int j = 0; j < 4; ++j) {
                ps[j] += acc[i][j];
                pq[j] += acc[i][j] * acc[i][j];
            }
        }
    }
    __syncthreads();
    float* redS = Xl;             // [8][128]
    float* redQ = Xl + 8 * 128;   // [8][128]
    ((float4*)(redS + rg * 128))[cg] = make_float4(ps[0], ps[1], ps[2], ps[3]);
    ((float4*)(redQ + rg * 128))[cg] = make_float4(pq[0], pq[1], pq[2], pq[3]);
    __syncthreads();
    if (t < DIM) {
        float s = 0.f, q = 0.f;
        #pragma unroll
        for (int r8 = 0; r8 < 8; ++r8) { s += redS[r8 * 128 + t]; q += redQ[r8 * 128 + t]; }
        atomicAdd(colsum + t, s);
        atomicAdd(colsq + t, q);
    }
}

// ======= final: score = sum_i pooled_i @ predW_i + predb_i =======
__global__ __launch_bounds__(64) void k_score(const float* __restrict__ pooled,
                                              const float* __restrict__ predW,
                                              const float* __restrict__ predb,
                                              float* __restrict__ out)
{
    int g = blockIdx.x;
    int o = threadIdx.x;
    float s = 0.f;
    for (int i = 0; i < 5; ++i) {
        const float* pr = pooled + (size_t)i * NG * DIM + (size_t)g * DIM;
        const float* Wp = predW + (size_t)i * DIM * OUTD;
        float acc = 0.f;
        #pragma unroll 4
        for (int k = 0; k < DIM; ++k) acc = fmaf(pr[k], Wp[k * OUTD + o], acc);
        s += acc + predb[i * OUTD + o];
    }
    out[(size_t)g * OUTD + o] = s;
}

extern "C" void kernel_launch(void* const* d_in, const int* in_sizes, int n_in,
                              void* d_out, int out_size, void* d_ws, size_t ws_size,
                              hipStream_t stream)
{
    const float* h     = (const float*)d_in[0];
    const int*   esrc  = (const int*)d_in[1];
    const int*   edst  = (const int*)d_in[2];
    const int*   gid   = (const int*)d_in[3];
    const float* W1    = (const float*)d_in[4];
    const float* bn1g  = (const float*)d_in[5];
    const float* bn1b  = (const float*)d_in[6];
    const float* W2    = (const float*)d_in[7];
    const float* bn2g  = (const float*)d_in[8];
    const float* bn2b  = (const float*)d_in[9];
    const float* predW = (const float*)d_in[10];
    const float* predb = (const float*)d_in[11];
    float* out = (float*)d_out;

    float* ws = (float*)d_ws;
    const size_t NF = (size_t)NN * DIM;        // 6.4M floats
    float* agg    = ws;
    float* z1     = ws + NF;
    float* Zb     = ws + 2 * NF;               // z2, reused every layer
    float* pooled = ws + 3 * NF;               // 5*128*128
    float* stats  = pooled + 5 * NG * DIM;     // 4 layers * 1024
    // per layer: [0]=sum1 [128]=sq1 [512]=sum2 [640]=sq2

    int* ideg   = (int*)(stats + NCONV * 1024);
    int* rowptr = ideg + NN;                   // NN+1
    int* cursor = rowptr + NN + 1;
    int* csr    = cursor + NN;                 // NE
    int* gstart = csr + NE;                    // NG+1
    int* bsum   = gstart + NG + 1;             // NB
    int* boff   = bsum + NB;                   // NB

    hipMemsetAsync(pooled, 0, (5 * NG * DIM + NCONV * 1024) * sizeof(float), stream);
    hipMemsetAsync(ideg, 0, NN * sizeof(int), stream);

    // build CSR (dst -> list of src) + graph boundaries
    k_degree<<<(NE + 255) / 256, 256, 0, stream>>>(edst, ideg);
    k_scan1<<<NB, 256, 0, stream>>>(ideg, bsum);
    k_scan2<<<1, 256, 0, stream>>>(bsum, boff);
    k_scan3<<<NB, 256, 0, stream>>>(ideg, boff, rowptr, cursor);
    k_fill<<<(NE + 255) / 256, 256, 0, stream>>>(esrc, edst, cursor, csr);
    k_bounds<<<(NN + 255) / 256, 256, 0, stream>>>(gid, gstart);

    // pooled[0] from the input h (no affine)
    k_poolseg<false><<<NG * 4, 256, 0, stream>>>(h, nullptr, nullptr, nullptr, nullptr,
                                                 gstart, pooled);

    for (int i = 0; i < NCONV; ++i) {
        float* st = stats + i * 1024;
        if (i == 0)
            k_gather<false><<<(NN + 7) / 8, 256, 0, stream>>>(
                h, nullptr, nullptr, nullptr, nullptr, rowptr, csr, agg);
        else {
            float* stp = stats + (i - 1) * 1024;
            k_gather<true><<<(NN + 7) / 8, 256, 0, stream>>>(
                Zb, stp + 512, stp + 640, bn2g + (i - 1) * DIM, bn2b + (i - 1) * DIM,
                rowptr, csr, agg);
        }
        k_gemm_bn<false><<<(NN + 63) / 64, 256, 0, stream>>>(
            agg, nullptr, nullptr, nullptr, nullptr,
            W1 + (size_t)i * DIM * DIM, z1, st, st + 128);
        k_gemm_bn<true><<<(NN + 63) / 64, 256, 0, stream>>>(
            z1, st, st + 128, bn1g + i * DIM, bn1b + i * DIM,
            W2 + (size_t)i * DIM * DIM, Zb, st + 512, st + 640);
        k_poolseg<true><<<NG * 4, 256, 0, stream>>>(
            Zb, st + 512, st + 640, bn2g + i * DIM, bn2b + i * DIM,
            gstart, pooled + (size_t)(i + 1) * NG * DIM);
    }

    k_score<<<NG, OUTD, 0, stream>>>(pooled, predW, predb, out);
}

// Round 10
// 785.119 us; speedup vs baseline: 13.4541x; 1.1204x over previous
//
#include <hip/hip_runtime.h>

#define NN 50000
#define NE 800000
#define NG 128
#define DIM 128
#define OUTD 64
#define NCONV 4
#define NB 196          // ceil(NN/256)
#define BN_EPS 1e-5f

typedef __attribute__((ext_vector_type(8))) short short8;
typedef __attribute__((ext_vector_type(4))) float f32x4;
union BF8 { uint4 u; short8 s; };

__device__ inline unsigned f2bf(float f) {   // RNE f32 -> bf16 bits
    unsigned u = __float_as_uint(f);
    return (u + 0x7FFFu + ((u >> 16) & 1u)) >> 16;
}

// ================= CSR build =================
__global__ __launch_bounds__(256) void k_degree(const int* __restrict__ dst,
                                                int* __restrict__ deg)
{
    int e = blockIdx.x * 256 + threadIdx.x;
    if (e < NE) atomicAdd(&deg[dst[e]], 1);
}

__global__ __launch_bounds__(256) void k_scan1(const int* __restrict__ deg,
                                               int* __restrict__ bsum)
{
    __shared__ int part[256];
    int t = threadIdx.x, idx = blockIdx.x * 256 + t;
    int v = (idx < NN) ? deg[idx] : 0;
    part[t] = v;
    __syncthreads();
    #pragma unroll
    for (int off = 1; off < 256; off <<= 1) {
        int u = (t >= off) ? part[t - off] : 0;
        __syncthreads();
        part[t] += u;
        __syncthreads();
    }
    if (t == 255) bsum[blockIdx.x] = part[255];
}

__global__ __launch_bounds__(256) void k_scan2(const int* __restrict__ bsum,
                                               int* __restrict__ boff)
{
    __shared__ int part[256];
    int t = threadIdx.x;
    int v = (t < NB) ? bsum[t] : 0;
    part[t] = v;
    __syncthreads();
    #pragma unroll
    for (int off = 1; off < 256; off <<= 1) {
        int u = (t >= off) ? part[t - off] : 0;
        __syncthreads();
        part[t] += u;
        __syncthreads();
    }
    if (t < NB) boff[t] = part[t] - v;   // exclusive
}

__global__ __launch_bounds__(256) void k_scan3(const int* __restrict__ deg,
                                               const int* __restrict__ boff,
                                               int* __restrict__ rowptr,
                                               int* __restrict__ cursor)
{
    __shared__ int part[256];
    int t = threadIdx.x, idx = blockIdx.x * 256 + t;
    int v = (idx < NN) ? deg[idx] : 0;
    part[t] = v;
    __syncthreads();
    #pragma unroll
    for (int off = 1; off < 256; off <<= 1) {
        int u = (t >= off) ? part[t - off] : 0;
        __syncthreads();
        part[t] += u;
        __syncthreads();
    }
    if (idx < NN) {
        int excl = part[t] - v + boff[blockIdx.x];
        rowptr[idx] = excl;
        cursor[idx] = excl;
    }
    if (idx == 0) rowptr[NN] = NE;
}

__global__ __launch_bounds__(256) void k_fill(const int* __restrict__ src,
                                              const int* __restrict__ dst,
                                              int* __restrict__ cursor,
                                              int* __restrict__ csr)
{
    int e = blockIdx.x * 256 + threadIdx.x;
    if (e >= NE) return;
    int pos = atomicAdd(&cursor[dst[e]], 1);
    csr[pos] = src[e];
}

__global__ __launch_bounds__(256) void k_bounds(const int* __restrict__ gid,
                                                int* __restrict__ gstart)
{
    int n = blockIdx.x * 256 + threadIdx.x;
    if (n >= NN) return;
    int g = gid[n];
    int gp = (n == 0) ? -1 : gid[n - 1];
    for (int x = gp + 1; x <= g; ++x) gstart[x] = n;
    if (n == NN - 1)
        for (int x = g + 1; x <= NG; ++x) gstart[x] = NN;
}

// ====== W -> bf16, MFMA-B fragment order: [mat][kk][ctg][lane][8] ======
__global__ __launch_bounds__(256) void k_wprep(const float* __restrict__ W1,
                                               const float* __restrict__ W2,
                                               unsigned short* __restrict__ Wbf)
{
    int tid = blockIdx.x * 256 + threadIdx.x;   // 16384
    int l   = tid & 63;
    int ctg = (tid >> 6) & 7;
    int kk  = (tid >> 9) & 3;
    int mat = tid >> 11;
    const float* Ws = (mat < 4) ? (W1 + (size_t)mat * DIM * DIM)
                                : (W2 + (size_t)(mat - 4) * DIM * DIM);
    int col = ctg * 16 + (l & 15);
    int k0  = kk * 32 + (l >> 4) * 8;
    unsigned sh[8];
    #pragma unroll
    for (int j = 0; j < 8; ++j) sh[j] = f2bf(Ws[(size_t)(k0 + j) * DIM + col]);
    uint4 pk;
    pk.x = sh[0] | (sh[1] << 16); pk.y = sh[2] | (sh[3] << 16);
    pk.z = sh[4] | (sh[5] << 16); pk.w = sh[6] | (sh[7] << 16);
    ((uint4*)Wbf)[tid] = pk;
}

// --- per-thread BN affine for 4 channels ch0..ch0+3 ---
__device__ inline void bn_affine4(const float* __restrict__ sumP,
                                  const float* __restrict__ sqP,
                                  const float* __restrict__ gP,
                                  const float* __restrict__ bP,
                                  int ch0, float4& av, float4& cv)
{
    const float invM = 1.f / (float)NN;
    #pragma unroll
    for (int j = 0; j < 4; ++j) {
        int ch = ch0 + j;
        float m = sumP[ch] * invM;
        float var = sqP[ch] * invM - m * m;
        float s = gP[ch] * rsqrtf(var + BN_EPS);
        (&av.x)[j] = s;
        (&cv.x)[j] = bP[ch] - m * s;
    }
}

__device__ inline float4 aff_relu(float4 v, const float4 av, const float4 cv)
{
    v.x = fmaxf(fmaf(v.x, av.x, cv.x), 0.f);
    v.y = fmaxf(fmaf(v.y, av.y, cv.y), 0.f);
    v.z = fmaxf(fmaf(v.z, av.z, cv.z), 0.f);
    v.w = fmaxf(fmaf(v.w, av.w, cv.w), 0.f);
    return v;
}

// ==== gather: agg[n] = f(h[n]) + sum_{s in N(n)} f(h[s]) ====
template<bool AFFINE>
__global__ __launch_bounds__(256) void k_gather(
    const float* __restrict__ h,
    const float* __restrict__ sumP, const float* __restrict__ sqP,
    const float* __restrict__ gP, const float* __restrict__ bP,
    const int* __restrict__ rowptr, const int* __restrict__ csr,
    float* __restrict__ agg)
{
    int t = threadIdx.x;
    int n = blockIdx.x * 8 + (t >> 5);
    if (n >= NN) return;
    int l = t & 31;
    float4 av, cv;
    if (AFFINE) bn_affine4(sumP, sqP, gP, bP, l * 4, av, cv);
    const float4* hp = (const float4*)h;
    float4 v = hp[(size_t)n * 32 + l];
    if (AFFINE) v = aff_relu(v, av, cv);
    int p = rowptr[n], end = rowptr[n + 1];
    for (; p + 4 <= end; p += 4) {
        int s0 = csr[p], s1 = csr[p + 1], s2 = csr[p + 2], s3 = csr[p + 3];
        float4 u0 = hp[(size_t)s0 * 32 + l];
        float4 u1 = hp[(size_t)s1 * 32 + l];
        float4 u2 = hp[(size_t)s2 * 32 + l];
        float4 u3 = hp[(size_t)s3 * 32 + l];
        if (AFFINE) {
            u0 = aff_relu(u0, av, cv); u1 = aff_relu(u1, av, cv);
            u2 = aff_relu(u2, av, cv); u3 = aff_relu(u3, av, cv);
        }
        v.x += u0.x + u1.x + u2.x + u3.x;
        v.y += u0.y + u1.y + u2.y + u3.y;
        v.z += u0.z + u1.z + u2.z + u3.z;
        v.w += u0.w + u1.w + u2.w + u3.w;
    }
    for (; p < end; ++p) {
        int s = csr[p];
        float4 u = hp[(size_t)s * 32 + l];
        if (AFFINE) u = aff_relu(u, av, cv);
        v.x += u.x; v.y += u.y; v.z += u.z; v.w += u.w;
    }
    ((float4*)agg)[(size_t)n * 32 + l] = v;
}

// ===== segmented pooling =====
template<bool AFFINE>
__global__ __launch_bounds__(256) void k_poolseg(
    const float* __restrict__ z,
    const float* __restrict__ sumP, const float* __restrict__ sqP,
    const float* __restrict__ gP, const float* __restrict__ bP,
    const int* __restrict__ gstart, float* __restrict__ pooled)
{
    const int g = blockIdx.x >> 2, split = blockIdx.x & 3;
    const int s = gstart[g], e = gstart[g + 1];
    const int len = e - s;
    const int chunk = (len + 3) >> 2;
    const int rs = s + split * chunk;
    const int re = min(e, rs + chunk);
    const int c4 = threadIdx.x & 31, rl = threadIdx.x >> 5;
    float4 av, cv;
    if (AFFINE) bn_affine4(sumP, sqP, gP, bP, c4 * 4, av, cv);
    float4 acc = make_float4(0.f, 0.f, 0.f, 0.f);
    for (int r = rs + rl; r < re; r += 8) {
        float4 v = ((const float4*)z)[(size_t)r * 32 + c4];
        if (AFFINE) v = aff_relu(v, av, cv);
        acc.x += v.x; acc.y += v.y; acc.z += v.z; acc.w += v.w;
    }
    __shared__ float4 red[8][32];
    red[rl][c4] = acc;
    __syncthreads();
    if (rl == 0) {
        float4 s4 = red[0][c4];
        #pragma unroll
        for (int r8 = 1; r8 < 8; ++r8) {
            float4 u = red[r8][c4];
            s4.x += u.x; s4.y += u.y; s4.z += u.z; s4.w += u.w;
        }
        float* p = pooled + (size_t)g * DIM + c4 * 4;
        atomicAdd(p + 0, s4.x);
        atomicAdd(p + 1, s4.y);
        atomicAdd(p + 2, s4.z);
        atomicAdd(p + 3, s4.w);
    }
}

// ============ MFMA bf16 GEMM + fused BN-in affine + BN-out stats ============
// 64-row tile, 256 threads (4 waves). wave w: rows (w>>1)*32..+31, cols (w&1)*64..+63.
// A staged in LDS in fragment order [rt4][kk4][lane64][8bf16], group stride 520 shorts.
template<bool AFFINE>
__global__ __launch_bounds__(256) void k_gemm_mfma(
    const float* __restrict__ X,
    const float* __restrict__ sumP, const float* __restrict__ sqP,
    const float* __restrict__ gP, const float* __restrict__ bP,
    const unsigned short* __restrict__ Wbf,     // fragment layout, one matrix
    float* __restrict__ Z,
    float* __restrict__ colsum, float* __restrict__ colsq)
{
    __shared__ unsigned short a_lds[16 * 520];   // 16.6 KB (padded groups)
    const int t = threadIdx.x;
    const int row0 = blockIdx.x * 64;

    { // ---- stage 64 rows of X -> bf16 fragments (fused affine+relu) ----
        const int q = t & 15;                    // k8-chunk, fixed per thread
        float av[8], cv[8];
        if (AFFINE) {
            const float invM = 1.f / (float)NN;
            #pragma unroll
            for (int j = 0; j < 8; ++j) {
                int ch = q * 8 + j;
                float m = sumP[ch] * invM;
                float var = sqP[ch] * invM - m * m;
                float sc = gP[ch] * rsqrtf(var + BN_EPS);
                av[j] = sc; cv[j] = bP[ch] - m * sc;
            }
        }
        #pragma unroll
        for (int it = 0; it < 4; ++it) {
            int id = t + it * 256;
            int row = id >> 4;                   // 0..63
            int grow = row0 + row;
            float4 x0 = make_float4(0.f, 0.f, 0.f, 0.f), x1 = x0;
            if (grow < NN) {
                const float4* Xv = (const float4*)(X + (size_t)grow * DIM + q * 8);
                x0 = Xv[0]; x1 = Xv[1];
            }
            float xv[8] = {x0.x, x0.y, x0.z, x0.w, x1.x, x1.y, x1.z, x1.w};
            unsigned sh[8];
            #pragma unroll
            for (int j = 0; j < 8; ++j) {
                float v = xv[j];
                if (AFFINE) v = fmaxf(fmaf(v, av[j], cv[j]), 0.f);
                sh[j] = f2bf(v);
            }
            uint4 pk;
            pk.x = sh[0] | (sh[1] << 16); pk.y = sh[2] | (sh[3] << 16);
            pk.z = sh[4] | (sh[5] << 16); pk.w = sh[6] | (sh[7] << 16);
            int g = (row >> 4) * 4 + (q >> 2);
            int l = (row & 15) + (q & 3) * 16;
            *(uint4*)(a_lds + g * 520 + l * 8) = pk;
        }
    }
    __syncthreads();

    const int w = t >> 6, lane = t & 63;
    const int rh = w >> 1, ch = w & 1;
    f32x4 acc[2][4];
    #pragma unroll
    for (int i = 0; i < 2; ++i)
        #pragma unroll
        for (int j = 0; j < 4; ++j) acc[i][j] = 0;

    const uint4* Wb = (const uint4*)Wbf;
    #pragma unroll
    for (int kk = 0; kk < 4; ++kk) {
        BF8 a[2], b[4];
        #pragma unroll
        for (int rti = 0; rti < 2; ++rti) {
            int g = (rh * 2 + rti) * 4 + kk;
            a[rti].u = *(const uint4*)(a_lds + g * 520 + lane * 8);
        }
        #pragma unroll
        for (int ct = 0; ct < 4; ++ct)
            b[ct].u = Wb[(kk * 8 + ch * 4 + ct) * 64 + lane];
        #pragma unroll
        for (int rti = 0; rti < 2; ++rti)
            #pragma unroll
            for (int ct = 0; ct < 4; ++ct)
                acc[rti][ct] = __builtin_amdgcn_mfma_f32_16x16x32_bf16(
                    a[rti].s, b[ct].s, acc[rti][ct], 0, 0, 0);
    }

    // ---- epilogue: store Z (fp32) + column stats ----
    float ps[4] = {0.f, 0.f, 0.f, 0.f}, pq[4] = {0.f, 0.f, 0.f, 0.f};
    #pragma unroll
    for (int rti = 0; rti < 2; ++rti) {
        #pragma unroll
        for (int r = 0; r < 4; ++r) {
            int grow = row0 + rh * 32 + rti * 16 + (lane >> 4) * 4 + r;
            if (grow < NN) {
                #pragma unroll
                for (int ct = 0; ct < 4; ++ct) {
                    float v = acc[rti][ct][r];
                    Z[(size_t)grow * DIM + ch * 64 + ct * 16 + (lane & 15)] = v;
                    ps[ct] += v;
                    pq[ct] += v * v;
                }
            }
        }
    }
    __syncthreads();                 // all LDS A-reads done
    float* red = (float*)a_lds;      // [256]: 0..127 sum, 128..255 sq
    red[t] = 0.f;
    __syncthreads();
    #pragma unroll
    for (int ct = 0; ct < 4; ++ct) {
        int col = ch * 64 + ct * 16 + (lane & 15);
        atomicAdd(&red[col], ps[ct]);
        atomicAdd(&red[128 + col], pq[ct]);
    }
    __syncthreads();
    if (t < DIM) {
        atomicAdd(colsum + t, red[t]);
        atomicAdd(colsq + t, red[128 + t]);
    }
}

// ======= final: score = sum_i pooled_i @ predW_i + predb_i =======
__global__ __launch_bounds__(64) void k_score(const float* __restrict__ pooled,
                                              const float* __restrict__ predW,
                                              const float* __restrict__ predb,
                                              float* __restrict__ out)
{
    int g = blockIdx.x;
    int o = threadIdx.x;
    float s = 0.f;
    for (int i = 0; i < 5; ++i) {
        const float* pr = pooled + (size_t)i * NG * DIM + (size_t)g * DIM;
        const float* Wp = predW + (size_t)i * DIM * OUTD;
        float acc = 0.f;
        #pragma unroll 4
        for (int k = 0; k < DIM; ++k) acc = fmaf(pr[k], Wp[k * OUTD + o], acc);
        s += acc + predb[i * OUTD + o];
    }
    out[(size_t)g * OUTD + o] = s;
}

extern "C" void kernel_launch(void* const* d_in, const int* in_sizes, int n_in,
                              void* d_out, int out_size, void* d_ws, size_t ws_size,
                              hipStream_t stream)
{
    const float* h     = (const float*)d_in[0];
    const int*   esrc  = (const int*)d_in[1];
    const int*   edst  = (const int*)d_in[2];
    const int*   gid   = (const int*)d_in[3];
    const float* W1    = (const float*)d_in[4];
    const float* bn1g  = (const float*)d_in[5];
    const float* bn1b  = (const float*)d_in[6];
    const float* W2    = (const float*)d_in[7];
    const float* bn2g  = (const float*)d_in[8];
    const float* bn2b  = (const float*)d_in[9];
    const float* predW = (const float*)d_in[10];
    const float* predb = (const float*)d_in[11];
    float* out = (float*)d_out;

    float* ws = (float*)d_ws;
    const size_t NF = (size_t)NN * DIM;        // 6.4M floats
    float* agg    = ws;
    float* z1     = ws + NF;
    float* Zb     = ws + 2 * NF;               // z2, reused every layer
    float* pooled = ws + 3 * NF;               // 5*128*128
    float* stats  = pooled + 5 * NG * DIM;     // 4 layers * 1024
    // per layer: [0]=sum1 [128]=sq1 [512]=sum2 [640]=sq2

    unsigned short* Wbf = (unsigned short*)(stats + NCONV * 1024);  // 8*16384 bf16
    int* ideg   = (int*)(Wbf + 8 * 16384);
    int* rowptr = ideg + NN;                   // NN+1
    int* cursor = rowptr + NN + 1;
    int* csr    = cursor + NN;                 // NE
    int* gstart = csr + NE;                    // NG+1
    int* bsum   = gstart + NG + 1;             // NB
    int* boff   = bsum + NB;                   // NB

    hipMemsetAsync(pooled, 0, (5 * NG * DIM + NCONV * 1024) * sizeof(float), stream);
    hipMemsetAsync(ideg, 0, NN * sizeof(int), stream);

    // W -> bf16 fragment layout (all 8 matrices), CSR, graph bounds
    k_wprep<<<64, 256, 0, stream>>>(W1, W2, Wbf);
    k_degree<<<(NE + 255) / 256, 256, 0, stream>>>(edst, ideg);
    k_scan1<<<NB, 256, 0, stream>>>(ideg, bsum);
    k_scan2<<<1, 256, 0, stream>>>(bsum, boff);
    k_scan3<<<NB, 256, 0, stream>>>(ideg, boff, rowptr, cursor);
    k_fill<<<(NE + 255) / 256, 256, 0, stream>>>(esrc, edst, cursor, csr);
    k_bounds<<<(NN + 255) / 256, 256, 0, stream>>>(gid, gstart);

    // pooled[0] from the input h (no affine)
    k_poolseg<false><<<NG * 4, 256, 0, stream>>>(h, nullptr, nullptr, nullptr, nullptr,
                                                 gstart, pooled);

    const int GB = (NN + 63) / 64;   // 782
    for (int i = 0; i < NCONV; ++i) {
        float* st = stats + i * 1024;
        if (i == 0)
            k_gather<false><<<(NN + 7) / 8, 256, 0, stream>>>(
                h, nullptr, nullptr, nullptr, nullptr, rowptr, csr, agg);
        else {
            float* stp = stats + (i - 1) * 1024;
            k_gather<true><<<(NN + 7) / 8, 256, 0, stream>>>(
                Zb, stp + 512, stp + 640, bn2g + (i - 1) * DIM, bn2b + (i - 1) * DIM,
                rowptr, csr, agg);
        }
        k_gemm_mfma<false><<<GB, 256, 0, stream>>>(
            agg, nullptr, nullptr, nullptr, nullptr,
            Wbf + (size_t)i * 16384, z1, st, st + 128);
        k_gemm_mfma<true><<<GB, 256, 0, stream>>>(
            z1, st, st + 128, bn1g + i * DIM, bn1b + i * DIM,
            Wbf + (size_t)(4 + i) * 16384, Zb, st + 512, st + 640);
        k_poolseg<true><<<NG * 4, 256, 0, stream>>>(
            Zb, st + 512, st + 640, bn2g + i * DIM, bn2b + i * DIM,
            gstart, pooled + (size_t)(i + 1) * NG * DIM);
    }

    k_score<<<NG, OUTD, 0, stream>>>(pooled, predW, predb, out);
}

// Round 13
// 624.029 us; speedup vs baseline: 16.9271x; 1.2581x over previous
//
#include <hip/hip_runtime.h>

#define NN 50000
#define NE 800000
#define NG 128
#define DIM 128
#define OUTD 64
#define NCONV 4
#define NB 196          // ceil(NN/256)
#define BN_EPS 1e-5f

typedef __attribute__((ext_vector_type(8))) short short8;
typedef __attribute__((ext_vector_type(4))) float f32x4;
union BF8 { uint4 u; short8 s; };

__device__ inline unsigned f2bf(float f) {   // RNE f32 -> bf16 bits
    unsigned u = __float_as_uint(f);
    return (u + 0x7FFFu + ((u >> 16) & 1u)) >> 16;
}
__device__ inline float bf_lo(unsigned u) { return __uint_as_float(u << 16); }
__device__ inline float bf_hi(unsigned u) { return __uint_as_float(u & 0xFFFF0000u); }

// ================= CSR build =================
__global__ __launch_bounds__(256) void k_degree(const int* __restrict__ dst,
                                                int* __restrict__ deg)
{
    int e = blockIdx.x * 256 + threadIdx.x;
    if (e < NE) atomicAdd(&deg[dst[e]], 1);
}

__global__ __launch_bounds__(256) void k_scan1(const int* __restrict__ deg,
                                               int* __restrict__ bsum)
{
    __shared__ int part[256];
    int t = threadIdx.x, idx = blockIdx.x * 256 + t;
    int v = (idx < NN) ? deg[idx] : 0;
    part[t] = v;
    __syncthreads();
    #pragma unroll
    for (int off = 1; off < 256; off <<= 1) {
        int u = (t >= off) ? part[t - off] : 0;
        __syncthreads();
        part[t] += u;
        __syncthreads();
    }
    if (t == 255) bsum[blockIdx.x] = part[255];
}

__global__ __launch_bounds__(256) void k_scan2(const int* __restrict__ bsum,
                                               int* __restrict__ boff)
{
    __shared__ int part[256];
    int t = threadIdx.x;
    int v = (t < NB) ? bsum[t] : 0;
    part[t] = v;
    __syncthreads();
    #pragma unroll
    for (int off = 1; off < 256; off <<= 1) {
        int u = (t >= off) ? part[t - off] : 0;
        __syncthreads();
        part[t] += u;
        __syncthreads();
    }
    if (t < NB) boff[t] = part[t] - v;   // exclusive
}

__global__ __launch_bounds__(256) void k_scan3(const int* __restrict__ deg,
                                               const int* __restrict__ boff,
                                               int* __restrict__ rowptr,
                                               int* __restrict__ cursor)
{
    __shared__ int part[256];
    int t = threadIdx.x, idx = blockIdx.x * 256 + t;
    int v = (idx < NN) ? deg[idx] : 0;
    part[t] = v;
    __syncthreads();
    #pragma unroll
    for (int off = 1; off < 256; off <<= 1) {
        int u = (t >= off) ? part[t - off] : 0;
        __syncthreads();
        part[t] += u;
        __syncthreads();
    }
    if (idx < NN) {
        int excl = part[t] - v + boff[blockIdx.x];
        rowptr[idx] = excl;
        cursor[idx] = excl;
    }
    if (idx == 0) rowptr[NN] = NE;
}

__global__ __launch_bounds__(256) void k_fill(const int* __restrict__ src,
                                              const int* __restrict__ dst,
                                              int* __restrict__ cursor,
                                              int* __restrict__ csr)
{
    int e = blockIdx.x * 256 + threadIdx.x;
    if (e >= NE) return;
    int pos = atomicAdd(&cursor[dst[e]], 1);
    csr[pos] = src[e];
}

__global__ __launch_bounds__(256) void k_bounds(const int* __restrict__ gid,
                                                int* __restrict__ gstart)
{
    int n = blockIdx.x * 256 + threadIdx.x;
    if (n >= NN) return;
    int g = gid[n];
    int gp = (n == 0) ? -1 : gid[n - 1];
    for (int x = gp + 1; x <= g; ++x) gstart[x] = n;
    if (n == NN - 1)
        for (int x = g + 1; x <= NG; ++x) gstart[x] = NN;
}

// ====== W -> bf16, MFMA-B fragment order: [mat][kk][ctg][lane][8] ======
__global__ __launch_bounds__(256) void k_wprep(const float* __restrict__ W1,
                                               const float* __restrict__ W2,
                                               unsigned short* __restrict__ Wbf)
{
    int tid = blockIdx.x * 256 + threadIdx.x;   // 16384
    int l   = tid & 63;
    int ctg = (tid >> 6) & 7;
    int kk  = (tid >> 9) & 3;
    int mat = tid >> 11;
    const float* Ws = (mat < 4) ? (W1 + (size_t)mat * DIM * DIM)
                                : (W2 + (size_t)(mat - 4) * DIM * DIM);
    int col = ctg * 16 + (l & 15);
    int k0  = kk * 32 + (l >> 4) * 8;
    unsigned sh[8];
    #pragma unroll
    for (int j = 0; j < 8; ++j) sh[j] = f2bf(Ws[(size_t)(k0 + j) * DIM + col]);
    uint4 pk;
    pk.x = sh[0] | (sh[1] << 16); pk.y = sh[2] | (sh[3] << 16);
    pk.z = sh[4] | (sh[5] << 16); pk.w = sh[6] | (sh[7] << 16);
    ((uint4*)Wbf)[tid] = pk;
}

// ====== fp32 -> bf16 bulk convert (layer-0 h) ======
__global__ __launch_bounds__(256) void k_cvt(const float* __restrict__ in,
                                             unsigned short* __restrict__ outb)
{
    int idx = blockIdx.x * 256 + threadIdx.x;   // per 4 elements
    if (idx >= NN * DIM / 4) return;
    float4 v = ((const float4*)in)[idx];
    uint2 pk;
    pk.x = f2bf(v.x) | (f2bf(v.y) << 16);
    pk.y = f2bf(v.z) | (f2bf(v.w) << 16);
    ((uint2*)outb)[idx] = pk;
}

// --- per-thread BN affine for 4 channels ch0..ch0+3 ---
__device__ inline void bn_affine4(const float* __restrict__ sumP,
                                  const float* __restrict__ sqP,
                                  const float* __restrict__ gP,
                                  const float* __restrict__ bP,
                                  int ch0, float4& av, float4& cv)
{
    const float invM = 1.f / (float)NN;
    #pragma unroll
    for (int j = 0; j < 4; ++j) {
        int ch = ch0 + j;
        float m = sumP[ch] * invM;
        float var = sqP[ch] * invM - m * m;
        float s = gP[ch] * rsqrtf(var + BN_EPS);
        (&av.x)[j] = s;
        (&cv.x)[j] = bP[ch] - m * s;
    }
}

__device__ inline float4 aff_relu(float4 v, const float4 av, const float4 cv)
{
    v.x = fmaxf(fmaf(v.x, av.x, cv.x), 0.f);
    v.y = fmaxf(fmaf(v.y, av.y, cv.y), 0.f);
    v.z = fmaxf(fmaf(v.z, av.z, cv.z), 0.f);
    v.w = fmaxf(fmaf(v.w, av.w, cv.w), 0.f);
    return v;
}

// ==== gather (bf16): aggbf[n] = hbf[n] + sum_{s in N(n)} hbf[s], fp32 accum ====
__global__ __launch_bounds__(256) void k_gather_bf(
    const unsigned short* __restrict__ hbf,
    const int* __restrict__ rowptr, const int* __restrict__ csr,
    unsigned short* __restrict__ aggbf)
{
    int t = threadIdx.x;
    int n = blockIdx.x * 8 + (t >> 5);
    if (n >= NN) return;
    int l = t & 31;
    const uint2* hp = (const uint2*)hbf;     // 4 bf16 per uint2
    uint2 v0 = hp[(size_t)n * 32 + l];
    float a0 = bf_lo(v0.x), a1 = bf_hi(v0.x), a2 = bf_lo(v0.y), a3 = bf_hi(v0.y);
    int p = rowptr[n], end = rowptr[n + 1];
    for (; p + 4 <= end; p += 4) {
        int s0 = csr[p], s1 = csr[p + 1], s2 = csr[p + 2], s3 = csr[p + 3];
        uint2 u0 = hp[(size_t)s0 * 32 + l];
        uint2 u1 = hp[(size_t)s1 * 32 + l];
        uint2 u2 = hp[(size_t)s2 * 32 + l];
        uint2 u3 = hp[(size_t)s3 * 32 + l];
        a0 += bf_lo(u0.x) + bf_lo(u1.x) + bf_lo(u2.x) + bf_lo(u3.x);
        a1 += bf_hi(u0.x) + bf_hi(u1.x) + bf_hi(u2.x) + bf_hi(u3.x);
        a2 += bf_lo(u0.y) + bf_lo(u1.y) + bf_lo(u2.y) + bf_lo(u3.y);
        a3 += bf_hi(u0.y) + bf_hi(u1.y) + bf_hi(u2.y) + bf_hi(u3.y);
    }
    for (; p < end; ++p) {
        uint2 u = hp[(size_t)csr[p] * 32 + l];
        a0 += bf_lo(u.x); a1 += bf_hi(u.x); a2 += bf_lo(u.y); a3 += bf_hi(u.y);
    }
    uint2 pk;
    pk.x = f2bf(a0) | (f2bf(a1) << 16);
    pk.y = f2bf(a2) | (f2bf(a3) << 16);
    ((uint2*)aggbf)[(size_t)n * 32 + l] = pk;
}

// ===== segmented pooling (+ optional bf16 h-out for next layer's gather) =====
template<bool AFFINE, bool WRITEH>
__global__ __launch_bounds__(256) void k_poolseg(
    const float* __restrict__ z,
    const float* __restrict__ sumP, const float* __restrict__ sqP,
    const float* __restrict__ gP, const float* __restrict__ bP,
    const int* __restrict__ gstart, float* __restrict__ pooled,
    unsigned short* __restrict__ hbf)
{
    const int g = blockIdx.x >> 2, split = blockIdx.x & 3;
    const int s = gstart[g], e = gstart[g + 1];
    const int len = e - s;
    const int chunk = (len + 3) >> 2;
    const int rs = s + split * chunk;
    const int re = min(e, rs + chunk);
    const int c4 = threadIdx.x & 31, rl = threadIdx.x >> 5;
    float4 av, cv;
    if (AFFINE) bn_affine4(sumP, sqP, gP, bP, c4 * 4, av, cv);
    float4 acc = make_float4(0.f, 0.f, 0.f, 0.f);
    for (int r = rs + rl; r < re; r += 8) {
        float4 v = ((const float4*)z)[(size_t)r * 32 + c4];
        if (AFFINE) v = aff_relu(v, av, cv);
        if (WRITEH) {
            uint2 pk;
            pk.x = f2bf(v.x) | (f2bf(v.y) << 16);
            pk.y = f2bf(v.z) | (f2bf(v.w) << 16);
            ((uint2*)(hbf + (size_t)r * DIM))[c4] = pk;
        }
        acc.x += v.x; acc.y += v.y; acc.z += v.z; acc.w += v.w;
    }
    __shared__ float4 red[8][32];
    red[rl][c4] = acc;
    __syncthreads();
    if (rl == 0) {
        float4 s4 = red[0][c4];
        #pragma unroll
        for (int r8 = 1; r8 < 8; ++r8) {
            float4 u = red[r8][c4];
            s4.x += u.x; s4.y += u.y; s4.z += u.z; s4.w += u.w;
        }
        float* p = pooled + (size_t)g * DIM + c4 * 4;
        atomicAdd(p + 0, s4.x);
        atomicAdd(p + 1, s4.y);
        atomicAdd(p + 2, s4.z);
        atomicAdd(p + 3, s4.w);
    }
}

// ============ MFMA bf16 GEMM + fused BN-in affine + BN-out stats ============
// ABF16=true : X is bf16 (aggbf), channel-major rows — pure fragment copy.
// ABF16=false: X is fp32 (z1), BN1 affine+relu fused on stage-in.
// 64-row tile, 256 threads (4 waves). wave w: rows (w>>1)*32..+31, cols (w&1)*64..+63.
template<bool ABF16>
__global__ __launch_bounds__(256) void k_gemm_mfma(
    const void* __restrict__ Xv_,
    const float* __restrict__ sumP, const float* __restrict__ sqP,
    const float* __restrict__ gP, const float* __restrict__ bP,
    const unsigned short* __restrict__ Wbf,     // fragment layout, one matrix
    float* __restrict__ Z,
    float* __restrict__ colsum, float* __restrict__ colsq)
{
    __shared__ unsigned short a_lds[16 * 520];   // 16.6 KB (padded groups)
    const int t = threadIdx.x;
    const int row0 = blockIdx.x * 64;
    const int q = t & 15;                        // k8-chunk, fixed per thread

    if (ABF16) { // ---- stage: direct bf16 fragment copy ----
        const unsigned short* Xb = (const unsigned short*)Xv_;
        #pragma unroll
        for (int it = 0; it < 4; ++it) {
            int id = t + it * 256;
            int row = id >> 4;                   // 0..63
            int grow = row0 + row;
            uint4 pk = make_uint4(0, 0, 0, 0);
            if (grow < NN) pk = ((const uint4*)(Xb + (size_t)grow * DIM))[q];
            int g = (row >> 4) * 4 + (q >> 2);
            int l = (row & 15) + (q & 3) * 16;
            *(uint4*)(a_lds + g * 520 + l * 8) = pk;
        }
    } else {     // ---- stage: fp32 + BN1 affine/relu + cvt ----
        const float* X = (const float*)Xv_;
        float av[8], cv[8];
        {
            const float invM = 1.f / (float)NN;
            #pragma unroll
            for (int j = 0; j < 8; ++j) {
                int ch = q * 8 + j;
                float m = sumP[ch] * invM;
                float var = sqP[ch] * invM - m * m;
                float sc = gP[ch] * rsqrtf(var + BN_EPS);
                av[j] = sc; cv[j] = bP[ch] - m * sc;
            }
        }
        #pragma unroll
        for (int it = 0; it < 4; ++it) {
            int id = t + it * 256;
            int row = id >> 4;                   // 0..63
            int grow = row0 + row;
            float4 x0 = make_float4(0.f, 0.f, 0.f, 0.f), x1 = x0;
            if (grow < NN) {
                const float4* Xp = (const float4*)(X + (size_t)grow * DIM + q * 8);
                x0 = Xp[0]; x1 = Xp[1];
            }
            float xv[8] = {x0.x, x0.y, x0.z, x0.w, x1.x, x1.y, x1.z, x1.w};
            unsigned sh[8];
            #pragma unroll
            for (int j = 0; j < 8; ++j)
                sh[j] = f2bf(fmaxf(fmaf(xv[j], av[j], cv[j]), 0.f));
            uint4 pk;
            pk.x = sh[0] | (sh[1] << 16); pk.y = sh[2] | (sh[3] << 16);
            pk.z = sh[4] | (sh[5] << 16); pk.w = sh[6] | (sh[7] << 16);
            int g = (row >> 4) * 4 + (q >> 2);
            int l = (row & 15) + (q & 3) * 16;
            *(uint4*)(a_lds + g * 520 + l * 8) = pk;
        }
    }
    __syncthreads();

    const int w = t >> 6, lane = t & 63;
    const int rh = w >> 1, ch = w & 1;
    f32x4 acc[2][4];
    #pragma unroll
    for (int i = 0; i < 2; ++i)
        #pragma unroll
        for (int j = 0; j < 4; ++j) acc[i][j] = 0;

    const uint4* Wb = (const uint4*)Wbf;
    #pragma unroll
    for (int kk = 0; kk < 4; ++kk) {
        BF8 a[2], b[4];
        #pragma unroll
        for (int rti = 0; rti < 2; ++rti) {
            int g = (rh * 2 + rti) * 4 + kk;
            a[rti].u = *(const uint4*)(a_lds + g * 520 + lane * 8);
        }
        #pragma unroll
        for (int ct = 0; ct < 4; ++ct)
            b[ct].u = Wb[(kk * 8 + ch * 4 + ct) * 64 + lane];
        #pragma unroll
        for (int rti = 0; rti < 2; ++rti)
            #pragma unroll
            for (int ct = 0; ct < 4; ++ct)
                acc[rti][ct] = __builtin_amdgcn_mfma_f32_16x16x32_bf16(
                    a[rti].s, b[ct].s, acc[rti][ct], 0, 0, 0);
    }

    // ---- epilogue: store Z (fp32) + column stats ----
    float ps[4] = {0.f, 0.f, 0.f, 0.f}, pq[4] = {0.f, 0.f, 0.f, 0.f};
    #pragma unroll
    for (int rti = 0; rti < 2; ++rti) {
        #pragma unroll
        for (int r = 0; r < 4; ++r) {
            int grow = row0 + rh * 32 + rti * 16 + (lane >> 4) * 4 + r;
            if (grow < NN) {
                #pragma unroll
                for (int ct = 0; ct < 4; ++ct) {
                    float v = acc[rti][ct][r];
                    Z[(size_t)grow * DIM + ch * 64 + ct * 16 + (lane & 15)] = v;
                    ps[ct] += v;
                    pq[ct] += v * v;
                }
            }
        }
    }
    __syncthreads();                 // all LDS A-reads done
    float* red = (float*)a_lds;      // [256]: 0..127 sum, 128..255 sq
    red[t] = 0.f;
    __syncthreads();
    #pragma unroll
    for (int ct = 0; ct < 4; ++ct) {
        int col = ch * 64 + ct * 16 + (lane & 15);
        atomicAdd(&red[col], ps[ct]);
        atomicAdd(&red[128 + col], pq[ct]);
    }
    __syncthreads();
    if (t < DIM) {
        atomicAdd(colsum + t, red[t]);
        atomicAdd(colsq + t, red[128 + t]);
    }
}

// ======= final: out[g][o] = sum_i pooled_i[g] @ predW_i[:,o] + predb_i[o] =======
// One block per graph, 5 waves (one per rep), LDS reduce, single plain store.
// No atomics, no d_out pre-zeroing required — deterministic on every call.
__global__ __launch_bounds__(320) void k_score(const float* __restrict__ pooled,
                                               const float* __restrict__ predW,
                                               const float* __restrict__ predb,
                                               float* __restrict__ out)
{
    __shared__ float red[5][OUTD];
    const int g = blockIdx.x;
    const int w = threadIdx.x >> 6;      // rep 0..4
    const int o = threadIdx.x & 63;
    const float* pr = pooled + (size_t)w * NG * DIM + (size_t)g * DIM;
    const float* Wp = predW + (size_t)w * DIM * OUTD;
    float acc = predb[w * OUTD + o];
    #pragma unroll 8
    for (int k = 0; k < DIM; ++k) acc = fmaf(pr[k], Wp[k * OUTD + o], acc);
    red[w][o] = acc;
    __syncthreads();
    if (threadIdx.x < OUTD) {
        float s = red[0][o] + red[1][o] + red[2][o] + red[3][o] + red[4][o];
        out[(size_t)g * OUTD + o] = s;
    }
}

extern "C" void kernel_launch(void* const* d_in, const int* in_sizes, int n_in,
                              void* d_out, int out_size, void* d_ws, size_t ws_size,
                              hipStream_t stream)
{
    const float* h     = (const float*)d_in[0];
    const int*   esrc  = (const int*)d_in[1];
    const int*   edst  = (const int*)d_in[2];
    const int*   gid   = (const int*)d_in[3];
    const float* W1    = (const float*)d_in[4];
    const float* bn1g  = (const float*)d_in[5];
    const float* bn1b  = (const float*)d_in[6];
    const float* W2    = (const float*)d_in[7];
    const float* bn2g  = (const float*)d_in[8];
    const float* bn2b  = (const float*)d_in[9];
    const float* predW = (const float*)d_in[10];
    const float* predb = (const float*)d_in[11];
    float* out = (float*)d_out;

    float* ws = (float*)d_ws;
    const size_t NF = (size_t)NN * DIM;        // 6.4M elements
    float* z1     = ws;
    float* Zb     = ws + NF;
    float* pooled = ws + 2 * NF;               // 5*128*128
    float* stats  = pooled + 5 * NG * DIM;     // 4 layers * 1024
    // per layer: [0]=sum1 [128]=sq1 [512]=sum2 [640]=sq2

    unsigned short* hbf   = (unsigned short*)(stats + NCONV * 1024);  // NF bf16
    unsigned short* aggbf = hbf + NF;                                  // NF bf16
    unsigned short* Wbf   = aggbf + NF;                                // 8*16384 bf16
    int* ideg   = (int*)(Wbf + 8 * 16384);
    int* rowptr = ideg + NN;                   // NN+1
    int* cursor = rowptr + NN + 1;
    int* csr    = cursor + NN;                 // NE
    int* gstart = csr + NE;                    // NG+1
    int* bsum   = gstart + NG + 1;             // NB
    int* boff   = bsum + NB;                   // NB

    hipMemsetAsync(pooled, 0, (5 * NG * DIM + NCONV * 1024) * sizeof(float), stream);
    hipMemsetAsync(ideg, 0, NN * sizeof(int), stream);

    // W -> bf16 fragments, h -> bf16, CSR, graph bounds
    k_wprep<<<64, 256, 0, stream>>>(W1, W2, Wbf);
    k_cvt<<<(NN * DIM / 4 + 255) / 256, 256, 0, stream>>>(h, hbf);
    k_degree<<<(NE + 255) / 256, 256, 0, stream>>>(edst, ideg);
    k_scan1<<<NB, 256, 0, stream>>>(ideg, bsum);
    k_scan2<<<1, 256, 0, stream>>>(bsum, boff);
    k_scan3<<<NB, 256, 0, stream>>>(ideg, boff, rowptr, cursor);
    k_fill<<<(NE + 255) / 256, 256, 0, stream>>>(esrc, edst, cursor, csr);
    k_bounds<<<(NN + 255) / 256, 256, 0, stream>>>(gid, gstart);

    // pooled[0] from fp32 h (exact), no h-write
    k_poolseg<false, false><<<NG * 4, 256, 0, stream>>>(
        h, nullptr, nullptr, nullptr, nullptr, gstart, pooled, nullptr);

    const int GB = (NN + 63) / 64;   // 782
    for (int i = 0; i < NCONV; ++i) {
        float* st = stats + i * 1024;
        k_gather_bf<<<(NN + 7) / 8, 256, 0, stream>>>(hbf, rowptr, csr, aggbf);
        k_gemm_mfma<true><<<GB, 256, 0, stream>>>(
            aggbf, nullptr, nullptr, nullptr, nullptr,
            Wbf + (size_t)i * 16384, z1, st, st + 128);
        k_gemm_mfma<false><<<GB, 256, 0, stream>>>(
            z1, st, st + 128, bn1g + i * DIM, bn1b + i * DIM,
            Wbf + (size_t)(4 + i) * 16384, Zb, st + 512, st + 640);
        if (i < NCONV - 1)
            k_poolseg<true, true><<<NG * 4, 256, 0, stream>>>(
                Zb, st + 512, st + 640, bn2g + i * DIM, bn2b + i * DIM,
                gstart, pooled + (size_t)(i + 1) * NG * DIM, hbf);
        else
            k_poolseg<true, false><<<NG * 4, 256, 0, stream>>>(
                Zb, st + 512, st + 640, bn2g + i * DIM, bn2b + i * DIM,
                gstart, pooled + (size_t)(i + 1) * NG * DIM, nullptr);
    }

    k_score<<<NG, 320, 0, stream>>>(pooled, predW, predb, out);
}

// Round 14
// 618.446 us; speedup vs baseline: 17.0800x; 1.0090x over previous
//
#include <hip/hip_runtime.h>

#define NN 50000
#define NE 800000
#define NG 128
#define DIM 128
#define OUTD 64
#define NCONV 4
#define NB 196          // ceil(NN/256)
#define BN_EPS 1e-5f

typedef __attribute__((ext_vector_type(8))) short short8;
typedef __attribute__((ext_vector_type(4))) float f32x4;
union BF8 { uint4 u; short8 s; };

__device__ inline unsigned f2bf(float f) {   // RNE f32 -> bf16 bits
    unsigned u = __float_as_uint(f);
    return (u + 0x7FFFu + ((u >> 16) & 1u)) >> 16;
}
__device__ inline float bf_lo(unsigned u) { return __uint_as_float(u << 16); }
__device__ inline float bf_hi(unsigned u) { return __uint_as_float(u & 0xFFFF0000u); }

// ================= CSR build =================
__global__ __launch_bounds__(256) void k_degree(const int* __restrict__ dst,
                                                int* __restrict__ deg)
{
    int e = blockIdx.x * 256 + threadIdx.x;
    if (e < NE) atomicAdd(&deg[dst[e]], 1);
}

__global__ __launch_bounds__(256) void k_scan1(const int* __restrict__ deg,
                                               int* __restrict__ bsum)
{
    __shared__ int part[256];
    int t = threadIdx.x, idx = blockIdx.x * 256 + t;
    int v = (idx < NN) ? deg[idx] : 0;
    part[t] = v;
    __syncthreads();
    #pragma unroll
    for (int off = 1; off < 256; off <<= 1) {
        int u = (t >= off) ? part[t - off] : 0;
        __syncthreads();
        part[t] += u;
        __syncthreads();
    }
    if (t == 255) bsum[blockIdx.x] = part[255];
}

__global__ __launch_bounds__(256) void k_scan2(const int* __restrict__ bsum,
                                               int* __restrict__ boff)
{
    __shared__ int part[256];
    int t = threadIdx.x;
    int v = (t < NB) ? bsum[t] : 0;
    part[t] = v;
    __syncthreads();
    #pragma unroll
    for (int off = 1; off < 256; off <<= 1) {
        int u = (t >= off) ? part[t - off] : 0;
        __syncthreads();
        part[t] += u;
        __syncthreads();
    }
    if (t < NB) boff[t] = part[t] - v;   // exclusive
}

__global__ __launch_bounds__(256) void k_scan3(const int* __restrict__ deg,
                                               const int* __restrict__ boff,
                                               int* __restrict__ rowptr,
                                               int* __restrict__ cursor)
{
    __shared__ int part[256];
    int t = threadIdx.x, idx = blockIdx.x * 256 + t;
    int v = (idx < NN) ? deg[idx] : 0;
    part[t] = v;
    __syncthreads();
    #pragma unroll
    for (int off = 1; off < 256; off <<= 1) {
        int u = (t >= off) ? part[t - off] : 0;
        __syncthreads();
        part[t] += u;
        __syncthreads();
    }
    if (idx < NN) {
        int excl = part[t] - v + boff[blockIdx.x];
        rowptr[idx] = excl;
        cursor[idx] = excl;
    }
    if (idx == 0) rowptr[NN] = NE;
}

__global__ __launch_bounds__(256) void k_fill(const int* __restrict__ src,
                                              const int* __restrict__ dst,
                                              int* __restrict__ cursor,
                                              int* __restrict__ csr)
{
    int e = blockIdx.x * 256 + threadIdx.x;
    if (e >= NE) return;
    int pos = atomicAdd(&cursor[dst[e]], 1);
    csr[pos] = src[e];
}

__global__ __launch_bounds__(256) void k_bounds(const int* __restrict__ gid,
                                                int* __restrict__ gstart)
{
    int n = blockIdx.x * 256 + threadIdx.x;
    if (n >= NN) return;
    int g = gid[n];
    int gp = (n == 0) ? -1 : gid[n - 1];
    for (int x = gp + 1; x <= g; ++x) gstart[x] = n;
    if (n == NN - 1)
        for (int x = g + 1; x <= NG; ++x) gstart[x] = NN;
}

// ====== W -> bf16, MFMA-B fragment order: [mat][kk][ctg][lane][8] ======
__global__ __launch_bounds__(256) void k_wprep(const float* __restrict__ W1,
                                               const float* __restrict__ W2,
                                               unsigned short* __restrict__ Wbf)
{
    int tid = blockIdx.x * 256 + threadIdx.x;   // 16384
    int l   = tid & 63;
    int ctg = (tid >> 6) & 7;
    int kk  = (tid >> 9) & 3;
    int mat = tid >> 11;
    const float* Ws = (mat < 4) ? (W1 + (size_t)mat * DIM * DIM)
                                : (W2 + (size_t)(mat - 4) * DIM * DIM);
    int col = ctg * 16 + (l & 15);
    int k0  = kk * 32 + (l >> 4) * 8;
    unsigned sh[8];
    #pragma unroll
    for (int j = 0; j < 8; ++j) sh[j] = f2bf(Ws[(size_t)(k0 + j) * DIM + col]);
    uint4 pk;
    pk.x = sh[0] | (sh[1] << 16); pk.y = sh[2] | (sh[3] << 16);
    pk.z = sh[4] | (sh[5] << 16); pk.w = sh[6] | (sh[7] << 16);
    ((uint4*)Wbf)[tid] = pk;
}

// ====== fp32 -> bf16 bulk convert (layer-0 h) ======
__global__ __launch_bounds__(256) void k_cvt(const float* __restrict__ in,
                                             unsigned short* __restrict__ outb)
{
    int idx = blockIdx.x * 256 + threadIdx.x;   // per 4 elements
    if (idx >= NN * DIM / 4) return;
    float4 v = ((const float4*)in)[idx];
    uint2 pk;
    pk.x = f2bf(v.x) | (f2bf(v.y) << 16);
    pk.y = f2bf(v.z) | (f2bf(v.w) << 16);
    ((uint2*)outb)[idx] = pk;
}

// --- per-thread BN affine for 4 channels ch0..ch0+3 ---
__device__ inline void bn_affine4(const float* __restrict__ sumP,
                                  const float* __restrict__ sqP,
                                  const float* __restrict__ gP,
                                  const float* __restrict__ bP,
                                  int ch0, float4& av, float4& cv)
{
    const float invM = 1.f / (float)NN;
    #pragma unroll
    for (int j = 0; j < 4; ++j) {
        int ch = ch0 + j;
        float m = sumP[ch] * invM;
        float var = sqP[ch] * invM - m * m;
        float s = gP[ch] * rsqrtf(var + BN_EPS);
        (&av.x)[j] = s;
        (&cv.x)[j] = bP[ch] - m * s;
    }
}

__device__ inline float4 aff_relu(float4 v, const float4 av, const float4 cv)
{
    v.x = fmaxf(fmaf(v.x, av.x, cv.x), 0.f);
    v.y = fmaxf(fmaf(v.y, av.y, cv.y), 0.f);
    v.z = fmaxf(fmaf(v.z, av.z, cv.z), 0.f);
    v.w = fmaxf(fmaf(v.w, av.w, cv.w), 0.f);
    return v;
}

// ===== segmented pooling: reads bf16 z (or fp32 h), BN affine, pool + hbf =====
template<bool AFFINE, bool WRITEH, bool INBF16>
__global__ __launch_bounds__(256) void k_poolseg(
    const void* __restrict__ z_,
    const float* __restrict__ sumP, const float* __restrict__ sqP,
    const float* __restrict__ gP, const float* __restrict__ bP,
    const int* __restrict__ gstart, float* __restrict__ pooled,
    unsigned short* __restrict__ hbf)
{
    const int g = blockIdx.x >> 2, split = blockIdx.x & 3;
    const int s = gstart[g], e = gstart[g + 1];
    const int len = e - s;
    const int chunk = (len + 3) >> 2;
    const int rs = s + split * chunk;
    const int re = min(e, rs + chunk);
    const int c4 = threadIdx.x & 31, rl = threadIdx.x >> 5;
    float4 av, cv;
    if (AFFINE) bn_affine4(sumP, sqP, gP, bP, c4 * 4, av, cv);
    float4 acc = make_float4(0.f, 0.f, 0.f, 0.f);
    for (int r = rs + rl; r < re; r += 8) {
        float4 v;
        if (INBF16) {
            uint2 w = ((const uint2*)z_)[(size_t)r * 32 + c4];
            v = make_float4(bf_lo(w.x), bf_hi(w.x), bf_lo(w.y), bf_hi(w.y));
        } else {
            v = ((const float4*)z_)[(size_t)r * 32 + c4];
        }
        if (AFFINE) v = aff_relu(v, av, cv);
        if (WRITEH) {
            uint2 pk;
            pk.x = f2bf(v.x) | (f2bf(v.y) << 16);
            pk.y = f2bf(v.z) | (f2bf(v.w) << 16);
            ((uint2*)(hbf + (size_t)r * DIM))[c4] = pk;
        }
        acc.x += v.x; acc.y += v.y; acc.z += v.z; acc.w += v.w;
    }
    __shared__ float4 red[8][32];
    red[rl][c4] = acc;
    __syncthreads();
    if (rl == 0) {
        float4 s4 = red[0][c4];
        #pragma unroll
        for (int r8 = 1; r8 < 8; ++r8) {
            float4 u = red[r8][c4];
            s4.x += u.x; s4.y += u.y; s4.z += u.z; s4.w += u.w;
        }
        float* p = pooled + (size_t)g * DIM + c4 * 4;
        atomicAdd(p + 0, s4.x);
        atomicAdd(p + 1, s4.y);
        atomicAdd(p + 2, s4.z);
        atomicAdd(p + 3, s4.w);
    }
}

// ============ MFMA bf16 GEMM, bf16 in/out, fused gather or affine ============
// GATHER=true : X = hbf; stage computes CSR neighbor-sum per row (fp32 accum).
// GATHER=false, AFFINE=true: X = z1 bf16; BN1 affine+relu on stage-in.
// 64-row tile, 256 threads (4 waves). wave w: rows (w>>1)*32..+31, cols (w&1)*64..+63.
// Output Z bf16 + fp32 column stats (from fp32 accumulators — exact).
template<bool GATHER, bool AFFINE>
__global__ __launch_bounds__(256) void k_gemm_mfma(
    const unsigned short* __restrict__ Xb,
    const int* __restrict__ rowptr, const int* __restrict__ csr,
    const float* __restrict__ sumP, const float* __restrict__ sqP,
    const float* __restrict__ gP, const float* __restrict__ bP,
    const unsigned short* __restrict__ Wbf,     // fragment layout, one matrix
    unsigned short* __restrict__ Z,             // bf16 out
    float* __restrict__ colsum, float* __restrict__ colsq)
{
    __shared__ unsigned short a_lds[16 * 520];   // 16.6 KB (padded groups)
    const int t = threadIdx.x;
    const int row0 = blockIdx.x * 64;
    const int q = t & 15;                        // k8-chunk (8 channels), fixed

    float av[8], cv[8];
    if (AFFINE) {
        const float invM = 1.f / (float)NN;
        #pragma unroll
        for (int j = 0; j < 8; ++j) {
            int ch = q * 8 + j;
            float m = sumP[ch] * invM;
            float var = sqP[ch] * invM - m * m;
            float sc = gP[ch] * rsqrtf(var + BN_EPS);
            av[j] = sc; cv[j] = bP[ch] - m * sc;
        }
    }

    const uint4* hp4 = (const uint4*)Xb;         // row stride 16 uint4
    #pragma unroll
    for (int it = 0; it < 4; ++it) {
        int row = (t >> 4) + it * 16;            // 0..63
        int grow = row0 + row;
        uint4 pk = make_uint4(0, 0, 0, 0);
        if (grow < NN) {
            float a[8];
            uint4 v = hp4[(size_t)grow * 16 + q];
            a[0] = bf_lo(v.x); a[1] = bf_hi(v.x);
            a[2] = bf_lo(v.y); a[3] = bf_hi(v.y);
            a[4] = bf_lo(v.z); a[5] = bf_hi(v.z);
            a[6] = bf_lo(v.w); a[7] = bf_hi(v.w);
            if (GATHER) {
                int p = rowptr[grow], end = rowptr[grow + 1];
                for (; p + 2 <= end; p += 2) {
                    int s0 = csr[p], s1 = csr[p + 1];
                    uint4 u0 = hp4[(size_t)s0 * 16 + q];
                    uint4 u1 = hp4[(size_t)s1 * 16 + q];
                    a[0] += bf_lo(u0.x) + bf_lo(u1.x);
                    a[1] += bf_hi(u0.x) + bf_hi(u1.x);
                    a[2] += bf_lo(u0.y) + bf_lo(u1.y);
                    a[3] += bf_hi(u0.y) + bf_hi(u1.y);
                    a[4] += bf_lo(u0.z) + bf_lo(u1.z);
                    a[5] += bf_hi(u0.z) + bf_hi(u1.z);
                    a[6] += bf_lo(u0.w) + bf_lo(u1.w);
                    a[7] += bf_hi(u0.w) + bf_hi(u1.w);
                }
                if (p < end) {
                    uint4 u = hp4[(size_t)csr[p] * 16 + q];
                    a[0] += bf_lo(u.x); a[1] += bf_hi(u.x);
                    a[2] += bf_lo(u.y); a[3] += bf_hi(u.y);
                    a[4] += bf_lo(u.z); a[5] += bf_hi(u.z);
                    a[6] += bf_lo(u.w); a[7] += bf_hi(u.w);
                }
            }
            if (AFFINE) {
                #pragma unroll
                for (int j = 0; j < 8; ++j)
                    a[j] = fmaxf(fmaf(a[j], av[j], cv[j]), 0.f);
            }
            pk.x = f2bf(a[0]) | (f2bf(a[1]) << 16);
            pk.y = f2bf(a[2]) | (f2bf(a[3]) << 16);
            pk.z = f2bf(a[4]) | (f2bf(a[5]) << 16);
            pk.w = f2bf(a[6]) | (f2bf(a[7]) << 16);
        }
        int g = (row >> 4) * 4 + (q >> 2);
        int l = (row & 15) + (q & 3) * 16;
        *(uint4*)(a_lds + g * 520 + l * 8) = pk;
    }
    __syncthreads();

    const int w = t >> 6, lane = t & 63;
    const int rh = w >> 1, ch = w & 1;
    f32x4 acc[2][4];
    #pragma unroll
    for (int i = 0; i < 2; ++i)
        #pragma unroll
        for (int j = 0; j < 4; ++j) acc[i][j] = 0;

    const uint4* Wb = (const uint4*)Wbf;
    #pragma unroll
    for (int kk = 0; kk < 4; ++kk) {
        BF8 a[2], b[4];
        #pragma unroll
        for (int rti = 0; rti < 2; ++rti) {
            int g = (rh * 2 + rti) * 4 + kk;
            a[rti].u = *(const uint4*)(a_lds + g * 520 + lane * 8);
        }
        #pragma unroll
        for (int ct = 0; ct < 4; ++ct)
            b[ct].u = Wb[(kk * 8 + ch * 4 + ct) * 64 + lane];
        #pragma unroll
        for (int rti = 0; rti < 2; ++rti)
            #pragma unroll
            for (int ct = 0; ct < 4; ++ct)
                acc[rti][ct] = __builtin_amdgcn_mfma_f32_16x16x32_bf16(
                    a[rti].s, b[ct].s, acc[rti][ct], 0, 0, 0);
    }

    // ---- epilogue: store Z (bf16) + column stats from fp32 acc ----
    float ps[4] = {0.f, 0.f, 0.f, 0.f}, pq[4] = {0.f, 0.f, 0.f, 0.f};
    #pragma unroll
    for (int rti = 0; rti < 2; ++rti) {
        #pragma unroll
        for (int r = 0; r < 4; ++r) {
            int grow = row0 + rh * 32 + rti * 16 + (lane >> 4) * 4 + r;
            if (grow < NN) {
                #pragma unroll
                for (int ct = 0; ct < 4; ++ct) {
                    float v = acc[rti][ct][r];
                    Z[(size_t)grow * DIM + ch * 64 + ct * 16 + (lane & 15)] =
                        (unsigned short)f2bf(v);
                    ps[ct] += v;
                    pq[ct] += v * v;
                }
            }
        }
    }
    __syncthreads();                 // all LDS A-reads done
    float* red = (float*)a_lds;      // [256]: 0..127 sum, 128..255 sq
    red[t] = 0.f;
    __syncthreads();
    #pragma unroll
    for (int ct = 0; ct < 4; ++ct) {
        int col = ch * 64 + ct * 16 + (lane & 15);
        atomicAdd(&red[col], ps[ct]);
        atomicAdd(&red[128 + col], pq[ct]);
    }
    __syncthreads();
    if (t < DIM) {
        atomicAdd(colsum + t, red[t]);
        atomicAdd(colsq + t, red[128 + t]);
    }
}

// ======= final: out[g][o] = sum_i pooled_i[g] @ predW_i[:,o] + predb_i[o] =======
// One block per graph, 5 waves (one per rep), LDS reduce, single plain store.
__global__ __launch_bounds__(320) void k_score(const float* __restrict__ pooled,
                                               const float* __restrict__ predW,
                                               const float* __restrict__ predb,
                                               float* __restrict__ out)
{
    __shared__ float red[5][OUTD];
    const int g = blockIdx.x;
    const int w = threadIdx.x >> 6;      // rep 0..4
    const int o = threadIdx.x & 63;
    const float* pr = pooled + (size_t)w * NG * DIM + (size_t)g * DIM;
    const float* Wp = predW + (size_t)w * DIM * OUTD;
    float acc = predb[w * OUTD + o];
    #pragma unroll 8
    for (int k = 0; k < DIM; ++k) acc = fmaf(pr[k], Wp[k * OUTD + o], acc);
    red[w][o] = acc;
    __syncthreads();
    if (threadIdx.x < OUTD) {
        float s = red[0][o] + red[1][o] + red[2][o] + red[3][o] + red[4][o];
        out[(size_t)g * OUTD + o] = s;
    }
}

extern "C" void kernel_launch(void* const* d_in, const int* in_sizes, int n_in,
                              void* d_out, int out_size, void* d_ws, size_t ws_size,
                              hipStream_t stream)
{
    const float* h     = (const float*)d_in[0];
    const int*   esrc  = (const int*)d_in[1];
    const int*   edst  = (const int*)d_in[2];
    const int*   gid   = (const int*)d_in[3];
    const float* W1    = (const float*)d_in[4];
    const float* bn1g  = (const float*)d_in[5];
    const float* bn1b  = (const float*)d_in[6];
    const float* W2    = (const float*)d_in[7];
    const float* bn2g  = (const float*)d_in[8];
    const float* bn2b  = (const float*)d_in[9];
    const float* predW = (const float*)d_in[10];
    const float* predb = (const float*)d_in[11];
    float* out = (float*)d_out;

    float* ws = (float*)d_ws;
    const size_t NF = (size_t)NN * DIM;        // 6.4M elements
    float* pooled = ws;                        // 5*128*128
    float* stats  = pooled + 5 * NG * DIM;     // 4 layers * 1024
    // per layer: [0]=sum1 [128]=sq1 [512]=sum2 [640]=sq2

    unsigned short* hbf  = (unsigned short*)(stats + NCONV * 1024);  // NF bf16
    unsigned short* z1b  = hbf + NF;                                  // NF bf16
    unsigned short* z2b  = z1b + NF;                                  // NF bf16
    unsigned short* Wbf  = z2b + NF;                                  // 8*16384 bf16
    int* ideg   = (int*)(Wbf + 8 * 16384);
    int* rowptr = ideg + NN;                   // NN+1
    int* cursor = rowptr + NN + 1;
    int* csr    = cursor + NN;                 // NE
    int* gstart = csr + NE;                    // NG+1
    int* bsum   = gstart + NG + 1;             // NB
    int* boff   = bsum + NB;                   // NB

    hipMemsetAsync(pooled, 0, (5 * NG * DIM + NCONV * 1024) * sizeof(float), stream);
    hipMemsetAsync(ideg, 0, NN * sizeof(int), stream);

    // W -> bf16 fragments, h -> bf16, CSR, graph bounds
    k_wprep<<<64, 256, 0, stream>>>(W1, W2, Wbf);
    k_cvt<<<(NN * DIM / 4 + 255) / 256, 256, 0, stream>>>(h, hbf);
    k_degree<<<(NE + 255) / 256, 256, 0, stream>>>(edst, ideg);
    k_scan1<<<NB, 256, 0, stream>>>(ideg, bsum);
    k_scan2<<<1, 256, 0, stream>>>(bsum, boff);
    k_scan3<<<NB, 256, 0, stream>>>(ideg, boff, rowptr, cursor);
    k_fill<<<(NE + 255) / 256, 256, 0, stream>>>(esrc, edst, cursor, csr);
    k_bounds<<<(NN + 255) / 256, 256, 0, stream>>>(gid, gstart);

    // pooled[0] from fp32 h (exact), no affine, no h-write
    k_poolseg<false, false, false><<<NG * 4, 256, 0, stream>>>(
        h, nullptr, nullptr, nullptr, nullptr, gstart, pooled, nullptr);

    const int GB = (NN + 63) / 64;   // 782
    for (int i = 0; i < NCONV; ++i) {
        float* st = stats + i * 1024;
        // GEMM1: gather-fused (agg = hbf + neighbor sum), out z1 bf16 + stats1
        k_gemm_mfma<true, false><<<GB, 256, 0, stream>>>(
            hbf, rowptr, csr, nullptr, nullptr, nullptr, nullptr,
            Wbf + (size_t)i * 16384, z1b, st, st + 128);
        // GEMM2: BN1 affine+relu on stage-in, out z2 bf16 + stats2
        k_gemm_mfma<false, true><<<GB, 256, 0, stream>>>(
            z1b, nullptr, nullptr, st, st + 128, bn1g + i * DIM, bn1b + i * DIM,
            Wbf + (size_t)(4 + i) * 16384, z2b, st + 512, st + 640);
        // pool (+ write next-layer hbf except last layer)
        if (i < NCONV - 1)
            k_poolseg<true, true, true><<<NG * 4, 256, 0, stream>>>(
                z2b, st + 512, st + 640, bn2g + i * DIM, bn2b + i * DIM,
                gstart, pooled + (size_t)(i + 1) * NG * DIM, hbf);
        else
            k_poolseg<true, false, true><<<NG * 4, 256, 0, stream>>>(
                z2b, st + 512, st + 640, bn2g + i * DIM, bn2b + i * DIM,
                gstart, pooled + (size_t)(i + 1) * NG * DIM, nullptr);
    }

    k_score<<<NG, 320, 0, stream>>>(pooled, predW, predb, out);
}